// Round 5
// baseline (2678.004 us; speedup 1.0000x reference)
//
#include <hip/hip_runtime.h>
#include <stdint.h>

// Predictive-coding inference: LAYER_SZS=[1024,4096,4096,4096,1024], B=2048, 5 iters.
// GEMM: C[M,N] = A[M,K](bf16) @ W[N,K](bf16)^T, f32 accum, fused epilogues.
// m201-style schedule: BM=BN=256, BK=64, 8 waves (2x4), per-wave 128x64 output,
// 2-deep half-tile double buffer (128KB LDS), 4 phases/K-tile, counted vmcnt(4)
// gates (never 0 in loop), setprio around MFMA clusters, XOR bank-swizzle
// (pre-swizzled global source + swizzled ds_read, linear gload_lds dest).

typedef __attribute__((ext_vector_type(8))) __bf16 bf16x8;
typedef __attribute__((ext_vector_type(4))) float f32x4;

#define B_ 2048
#define HALF_SH 8192                 // shorts per half-tile (128 rows x 64 cols)
#define LDS_BYTES (8 * HALF_SH * 2)  // 131072

__device__ __forceinline__ unsigned short f2bf(float f) {
  union { float f; unsigned u; } v; v.f = f;
  unsigned u = v.u;
  u += 0x7FFFu + ((u >> 16) & 1u);
  return (unsigned short)(u >> 16);
}
__device__ __forceinline__ float bf2f(unsigned short s) {
  union { unsigned u; float f; } v; v.u = ((unsigned)s) << 16;
  return v.f;
}
__device__ __forceinline__ float fast_sig(float x) { return 1.0f / (1.0f + __expf(-x)); }
__device__ __forceinline__ float fast_tanh(float x) {
  return 1.0f - 2.0f / (__expf(2.0f * x) + 1.0f);
}
__device__ __forceinline__ void gload_lds16(const void* g, void* l) {
  __builtin_amdgcn_global_load_lds((const __attribute__((address_space(1))) void*)g,
                                   (__attribute__((address_space(3))) void*)l, 16, 0, 0);
}

// epilogue modes
#define M_ACT  0   // o0=t=tanh(acc); o1=relu(t)
#define M_ACTD 1   // + o2 = d = (relu(t)-t)(1-t^2)
#define M_SIG  2   // s=sig(acc); o0=(targ-s)s(1-s); fout=s
#define M_ERR  3   // o0(a) = relu(a + 0.1*acc - 0.1*(a - i0))
#define M_PRED 4   // t=tanh(acc); o0=t; o1=(i0 - t)(1-t^2)

struct GDesc {
  const unsigned short* A;   // [M,K]
  const unsigned short* W;   // [N,K]
  unsigned short* o0;
  unsigned short* o1;
  unsigned short* o2;
  const unsigned short* i0;
  const float* targ;
  float* fout;
  int K, N, nx, mode;
};

#define GATE(n) do { \
  asm volatile("s_waitcnt vmcnt(" #n ")" ::: "memory"); \
  __builtin_amdgcn_s_barrier(); \
  __builtin_amdgcn_sched_barrier(0); \
} while (0)

__global__ __launch_bounds__(512, 2) void gemm8p(GDesc d0, GDesc d1, GDesc d2) {
  const GDesc d = (blockIdx.z == 0) ? d0 : (blockIdx.z == 1 ? d1 : d2);
  if ((int)blockIdx.x >= d.nx) return;

  extern __shared__ __attribute__((aligned(16))) unsigned short lds[];
  unsigned short* Alds = lds;                 // [buf][h] x HALF_SH
  unsigned short* Blds = lds + 4 * HALF_SH;   // [buf][v] x HALF_SH

  const int tid = threadIdx.x;
  const int wid = tid >> 6, lane = tid & 63;
  const int wr = wid >> 2, wc = wid & 3;      // 2 x 4 waves
  const int q = lane >> 4, j16 = lane & 15, r3 = j16 & 7;
  const int row0 = blockIdx.y << 8;           // BM = 256
  const int col0 = blockIdx.x << 8;           // BN = 256
  const int K = d.K, N = d.N, nt = K >> 6;

  // staging per-thread constants (2 gload_lds per half-tile per thread)
  const int rbase = (wid << 3) + (lane >> 3);                 // 0..63
  const int csw   = ((lane & 7) ^ ((lane >> 3) & 7)) << 3;    // pre-swizzled chunk (shorts)
  const unsigned short* Ag = d.A + (size_t)row0 * K;
  const unsigned short* Bg = d.W + (size_t)col0 * K;
  const int ldst = wid << 9;                                  // wid*512 shorts

#define STAGE_A(buf_, h_, k0_) do { \
  unsigned short* slot_ = Alds + (((buf_) << 1) + (h_)) * HALF_SH; \
  _Pragma("unroll") \
  for (int i_ = 0; i_ < 2; ++i_) \
    gload_lds16(Ag + (size_t)(((h_) << 7) + (i_ << 6) + rbase) * K + (k0_) + csw, \
                slot_ + (i_ << 12) + ldst); \
} while (0)
#define STAGE_B(buf_, v_, k0_) do { \
  unsigned short* slot_ = Blds + (((buf_) << 1) + (v_)) * HALF_SH; \
  _Pragma("unroll") \
  for (int i_ = 0; i_ < 2; ++i_) \
    gload_lds16(Bg + (size_t)(((v_) << 7) + (i_ << 6) + rbase) * K + (k0_) + csw, \
                slot_ + (i_ << 12) + ldst); \
} while (0)

  // LDS read offsets (shorts), loop-invariant
  int aoff[4][2], boff[2][2];
#pragma unroll
  for (int m = 0; m < 4; ++m)
#pragma unroll
    for (int ks = 0; ks < 2; ++ks)
      aoff[m][ks] = (wr * 64 + m * 16 + j16) * 64 + (((ks * 4 + q) ^ r3) << 3);
#pragma unroll
  for (int n = 0; n < 2; ++n)
#pragma unroll
    for (int ks = 0; ks < 2; ++ks)
      boff[n][ks] = (wc * 32 + n * 16 + j16) * 64 + (((ks * 4 + q) ^ r3) << 3);

  f32x4 acc[8][4];
#pragma unroll
  for (int m = 0; m < 8; ++m)
#pragma unroll
    for (int n = 0; n < 4; ++n) acc[m][n] = (f32x4){0.f, 0.f, 0.f, 0.f};

  bf16x8 av[2][4], bv[2][2];

#define LDA(slot_) do { \
  _Pragma("unroll") \
  for (int ks_ = 0; ks_ < 2; ++ks_) \
    _Pragma("unroll") \
    for (int m_ = 0; m_ < 4; ++m_) \
      av[ks_][m_] = *(const bf16x8*)((slot_) + aoff[m_][ks_]); \
} while (0)
#define LDB(slot_) do { \
  _Pragma("unroll") \
  for (int ks_ = 0; ks_ < 2; ++ks_) \
    _Pragma("unroll") \
    for (int n_ = 0; n_ < 2; ++n_) \
      bv[ks_][n_] = *(const bf16x8*)((slot_) + boff[n_][ks_]); \
} while (0)
#define MM(mb_, nb_) do { \
  __builtin_amdgcn_s_setprio(1); \
  _Pragma("unroll") \
  for (int ks_ = 0; ks_ < 2; ++ks_) \
    _Pragma("unroll") \
    for (int m_ = 0; m_ < 4; ++m_) \
      _Pragma("unroll") \
      for (int n_ = 0; n_ < 2; ++n_) \
        acc[(mb_) + m_][(nb_) + n_] = __builtin_amdgcn_mfma_f32_16x16x32_bf16( \
            av[ks_][m_], bv[ks_][n_], acc[(mb_) + m_][(nb_) + n_], 0, 0, 0); \
  __builtin_amdgcn_s_setprio(0); \
} while (0)

  // prologue: tile 0's four halves (A0,B0,A1,B1) into buf 0
  STAGE_A(0, 0, 0);
  STAGE_B(0, 0, 0);
  STAGE_A(0, 1, 0);
  STAGE_B(0, 1, 0);

  for (int t = 0; t < nt; ++t) {
    const int buf = t & 1, nbuf = buf ^ 1;
    const int kn = (t + 1 < nt) ? ((t + 1) << 6) : 0;   // dummy wrap-stage on last tile
    const unsigned short* As0 = Alds + ((buf << 1) + 0) * HALF_SH;
    const unsigned short* As1 = Alds + ((buf << 1) + 1) * HALF_SH;
    const unsigned short* Bs0 = Blds + ((buf << 1) + 0) * HALF_SH;
    const unsigned short* Bs1 = Blds + ((buf << 1) + 1) * HALF_SH;

    // phase 0: (h0,v0) — needs A0(t),B0(t); stages A0(t+1)
    GATE(4);
    LDA(As0); LDB(Bs0);
    STAGE_A(nbuf, 0, kn);
    MM(0, 0);
    // phase 1: (h1,v0) — needs A1(t); bv held; stages B0(t+1)
    GATE(4);
    LDA(As1);
    STAGE_B(nbuf, 0, kn);
    MM(4, 0);
    // phase 2: (h1,v1) — needs B1(t); av held; stages A1(t+1)
    GATE(4);
    LDB(Bs1);
    STAGE_A(nbuf, 1, kn);
    MM(4, 2);
    // phase 3: (h0,v1) — re-read A0(t); stages B1(t+1)
    GATE(6);
    LDA(As0);
    STAGE_B(nbuf, 1, kn);
    MM(0, 2);
  }

  // epilogue: per frag (m,n): h=m>>2, v=n>>1; D row=(lane>>4)*4+j, col=lane&15
#define IDX (size_t)(row0 + ((m >> 2) << 7) + wr * 64 + (m & 3) * 16 + (q << 2) + j) * N \
          + (col0 + ((n >> 1) << 7) + wc * 32 + (n & 1) * 16 + j16)
  if (d.mode == M_ACT) {
#pragma unroll
    for (int m = 0; m < 8; ++m)
#pragma unroll
      for (int n = 0; n < 4; ++n)
#pragma unroll
        for (int j = 0; j < 4; ++j) {
          const size_t idx = IDX;
          float t = fast_tanh(acc[m][n][j]);
          d.o0[idx] = f2bf(t);
          d.o1[idx] = f2bf(fmaxf(t, 0.f));
        }
  } else if (d.mode == M_ACTD) {
#pragma unroll
    for (int m = 0; m < 8; ++m)
#pragma unroll
      for (int n = 0; n < 4; ++n)
#pragma unroll
        for (int j = 0; j < 4; ++j) {
          const size_t idx = IDX;
          float t = fast_tanh(acc[m][n][j]);
          d.o0[idx] = f2bf(t);
          d.o1[idx] = f2bf(fmaxf(t, 0.f));
          d.o2[idx] = f2bf(t >= 0.f ? 0.f : (-t) * (1.f - t * t));
        }
  } else if (d.mode == M_SIG) {
#pragma unroll
    for (int m = 0; m < 8; ++m)
#pragma unroll
      for (int n = 0; n < 4; ++n)
#pragma unroll
        for (int j = 0; j < 4; ++j) {
          const size_t idx = IDX;
          float s = fast_sig(acc[m][n][j]);
          d.fout[idx] = s;
          d.o0[idx] = f2bf((d.targ[idx] - s) * s * (1.f - s));
        }
  } else if (d.mode == M_ERR) {
#pragma unroll
    for (int m = 0; m < 8; ++m)
#pragma unroll
      for (int n = 0; n < 4; ++n)
#pragma unroll
        for (int j = 0; j < 4; ++j) {
          const size_t idx = IDX;
          float a = bf2f(d.o0[idx]);
          float tp = bf2f(d.i0[idx]);
          d.o0[idx] = f2bf(fmaxf(a + 0.1f * acc[m][n][j] - 0.1f * (a - tp), 0.f));
        }
  } else {  // M_PRED
#pragma unroll
    for (int m = 0; m < 8; ++m)
#pragma unroll
      for (int n = 0; n < 4; ++n)
#pragma unroll
        for (int j = 0; j < 4; ++j) {
          const size_t idx = IDX;
          float t = fast_tanh(acc[m][n][j]);
          d.o0[idx] = f2bf(t);
          float an = bf2f(d.i0[idx]);
          d.o1[idx] = f2bf((an - t) * (1.f - t * t));
        }
  }
#undef IDX
}

// ---------------- batched f32 -> bf16 conversion (8 jobs, one launch) ----------
struct CvtJobs {
  const float* src[8];
  unsigned short* dst[8];
  int n4[8];
};
__global__ void k_cvt8(CvtJobs J) {
  const int jb = blockIdx.y;
  const float* s = J.src[jb];
  unsigned short* dd = J.dst[jb];
  const int n4 = J.n4[jb];
  int i = blockIdx.x * blockDim.x + threadIdx.x, st = gridDim.x * blockDim.x;
  for (; i < n4; i += st) {
    float4 v = ((const float4*)s)[i];
    ushort4 o; o.x = f2bf(v.x); o.y = f2bf(v.y); o.z = f2bf(v.z); o.w = f2bf(v.w);
    ((ushort4*)dd)[i] = o;
  }
}

// ------------------------------------------------------------------------------------
extern "C" void kernel_launch(void* const* d_in, const int* in_sizes, int n_in,
                              void* d_out, int out_size, void* d_ws, size_t ws_size,
                              hipStream_t stream) {
  (void)in_sizes; (void)n_in; (void)out_size; (void)ws_size;
  const float* x      = (const float*)d_in[0];
  const float* target = (const float*)d_in[1];
  const float* wSrc[7] = {(const float*)d_in[2], (const float*)d_in[3],
                          (const float*)d_in[4], (const float*)d_in[5],
                          (const float*)d_in[6], (const float*)d_in[7],
                          (const float*)d_in[8]};
  const size_t wN[7] = {(size_t)4096 * 1024, (size_t)4096 * 4096, (size_t)4096 * 4096,
                        (size_t)1024 * 4096, (size_t)4096 * 4096, (size_t)4096 * 4096,
                        (size_t)4096 * 1024};

  char* w = (char*)d_ws;
  size_t off = 0;
  auto alloc = [&](size_t bytes) { void* p = w + off; off += bytes; return p; };

  const size_t BIG = (size_t)B_ * 4096;
  const size_t SML = (size_t)B_ * 1024;
  unsigned short* xb  = (unsigned short*)alloc(SML * 2);
  unsigned short* a1b = (unsigned short*)alloc(BIG * 2);
  unsigned short* a2b = (unsigned short*)alloc(BIG * 2);
  unsigned short* a3b = (unsigned short*)alloc(BIG * 2);
  unsigned short* t0b = (unsigned short*)alloc(BIG * 2);
  unsigned short* t1b = (unsigned short*)alloc(BIG * 2);
  unsigned short* t2b = (unsigned short*)alloc(BIG * 2);
  unsigned short* d1b = (unsigned short*)alloc(BIG * 2);
  unsigned short* d2b = (unsigned short*)alloc(BIG * 2);
  unsigned short* d3b = (unsigned short*)alloc(SML * 2);
  unsigned short* Wb[7];
  for (int i = 0; i < 7; ++i) Wb[i] = (unsigned short*)alloc(wN[i] * 2);

  // ---- conversions: one batched launch ----
  CvtJobs J;
  for (int i = 0; i < 7; ++i) { J.src[i] = wSrc[i]; J.dst[i] = Wb[i]; J.n4[i] = (int)(wN[i] >> 2); }
  J.src[7] = x; J.dst[7] = xb; J.n4[7] = (int)(SML >> 2);
  k_cvt8<<<dim3(2048, 8), 256, 0, stream>>>(J);

  float* out = (float*)d_out;
  auto desc = [&](const unsigned short* A, const unsigned short* W_, int K, int N, int nx,
                  int mode, unsigned short* o0, unsigned short* o1, unsigned short* o2,
                  const unsigned short* i0, const float* targ, float* fout) {
    GDesc g; g.A = A; g.W = W_; g.o0 = o0; g.o1 = o1; g.o2 = o2; g.i0 = i0;
    g.targ = targ; g.fout = fout; g.K = K; g.N = N; g.nx = nx; g.mode = mode;
    return g;
  };

  // ---- initial feedforward (d1,d2 fused into g1/g2 epilogues) ----
  {
    GDesc g0 = desc(xb,  Wb[0], 1024, 4096, 16, M_ACT,  t0b, a1b, nullptr, nullptr, nullptr, nullptr);
    gemm8p<<<dim3(16, 8, 1), 512, LDS_BYTES, stream>>>(g0, g0, g0);
    GDesc g1 = desc(a1b, Wb[1], 4096, 4096, 16, M_ACTD, t1b, a2b, d1b, nullptr, nullptr, nullptr);
    gemm8p<<<dim3(16, 8, 1), 512, LDS_BYTES, stream>>>(g1, g1, g1);
    GDesc g2 = desc(a2b, Wb[2], 4096, 4096, 16, M_ACTD, t2b, a3b, d2b, nullptr, nullptr, nullptr);
    gemm8p<<<dim3(16, 8, 1), 512, LDS_BYTES, stream>>>(g2, g2, g2);
    GDesc g3 = desc(a3b, Wb[3], 4096, 1024, 4,  M_SIG,  d3b, nullptr, nullptr, nullptr, target, out);
    gemm8p<<<dim3(4, 8, 1), 512, LDS_BYTES, stream>>>(g3, g3, g3);
  }

  // ---- 5 inference iterations: 2 batched launches each ----
  for (int it = 0; it < 5; ++it) {
    GDesc e0 = desc(d1b, Wb[4], 4096, 4096, 16, M_ERR, a1b, nullptr, nullptr, t0b, nullptr, nullptr);
    GDesc e1 = desc(d2b, Wb[5], 4096, 4096, 16, M_ERR, a2b, nullptr, nullptr, t1b, nullptr, nullptr);
    GDesc e2 = desc(d3b, Wb[6], 1024, 4096, 16, M_ERR, a3b, nullptr, nullptr, t2b, nullptr, nullptr);
    gemm8p<<<dim3(16, 8, 3), 512, LDS_BYTES, stream>>>(e0, e1, e2);
    GDesc p0 = desc(a1b, Wb[1], 4096, 4096, 16, M_PRED, t1b, d1b, nullptr, a2b, nullptr, nullptr);
    GDesc p1 = desc(a2b, Wb[2], 4096, 4096, 16, M_PRED, t2b, d2b, nullptr, a3b, nullptr, nullptr);
    GDesc p2 = desc(a3b, Wb[3], 4096, 1024, 4,  M_SIG,  d3b, nullptr, nullptr, nullptr, target, out);
    gemm8p<<<dim3(16, 8, 3), 512, LDS_BYTES, stream>>>(p0, p1, p2);
  }
}

// Round 6
// 2572.730 us; speedup vs baseline: 1.0409x; 1.0409x over previous
//
#include <hip/hip_runtime.h>
#include <stdint.h>

// Predictive-coding inference: LAYER_SZS=[1024,4096,4096,4096,1024], B=2048, 5 iters.
// GEMM: C[M,N] = A[M,K](bf16) @ W[N,K](bf16)^T, f32 accum, fused epilogues.
// m201-discipline schedule: BM=BN=256, BK=64, 8 waves (2x4), per-wave 128x64 out,
// 2-deep half-tile double buffer (128KB LDS), 4 phases/K-tile in snake order
// (h0v0, h0v1, h1v1, h1v0) with dual-bv register sets (24 ds_read_b128/tile/wave,
// phase 3 read-free). Per phase: vmcnt(4) gate + barrier + ds_read + 1 half stage
// + setprio'd 16-MFMA cluster. No sched_barrier, no lgkmcnt asm (compiler-precise).

typedef __attribute__((ext_vector_type(8))) __bf16 bf16x8;
typedef __attribute__((ext_vector_type(4))) float f32x4;

#define B_ 2048
#define HALF_SH 8192                 // shorts per half-tile (128 rows x 64 cols)
#define LDS_BYTES (8 * HALF_SH * 2)  // 131072

__device__ __forceinline__ unsigned short f2bf(float f) {
  union { float f; unsigned u; } v; v.f = f;
  unsigned u = v.u;
  u += 0x7FFFu + ((u >> 16) & 1u);
  return (unsigned short)(u >> 16);
}
__device__ __forceinline__ float bf2f(unsigned short s) {
  union { unsigned u; float f; } v; v.u = ((unsigned)s) << 16;
  return v.f;
}
__device__ __forceinline__ float fast_sig(float x) { return 1.0f / (1.0f + __expf(-x)); }
__device__ __forceinline__ float fast_tanh(float x) {
  return 1.0f - 2.0f / (__expf(2.0f * x) + 1.0f);
}
__device__ __forceinline__ void gload_lds16(const void* g, void* l) {
  __builtin_amdgcn_global_load_lds((const __attribute__((address_space(1))) void*)g,
                                   (__attribute__((address_space(3))) void*)l, 16, 0, 0);
}

// epilogue modes
#define M_ACT  0   // o0=t=tanh(acc); o1=relu(t)
#define M_ACTD 1   // + o2 = d = (relu(t)-t)(1-t^2)
#define M_SIG  2   // s=sig(acc); o0=(targ-s)s(1-s); fout=s
#define M_ERR  3   // o0(a) = relu(a + 0.1*acc - 0.1*(a - i0))
#define M_PRED 4   // t=tanh(acc); o0=t; o1=(i0 - t)(1-t^2)

struct GDesc {
  const unsigned short* A;   // [M,K]
  const unsigned short* W;   // [N,K]
  unsigned short* o0;
  unsigned short* o1;
  unsigned short* o2;
  const unsigned short* i0;
  const float* targ;
  float* fout;
  int K, N, nx, mode;
};

__global__ __launch_bounds__(512, 2) void gemm8p(GDesc d0, GDesc d1, GDesc d2) {
  const GDesc d = (blockIdx.z == 0) ? d0 : (blockIdx.z == 1 ? d1 : d2);
  if ((int)blockIdx.x >= d.nx) return;

  extern __shared__ __attribute__((aligned(16))) unsigned short lds[];
  unsigned short* Alds = lds;                 // [buf][h] x HALF_SH
  unsigned short* Blds = lds + 4 * HALF_SH;   // [buf][v] x HALF_SH

  const int tid = threadIdx.x;
  const int wid = tid >> 6, lane = tid & 63;
  const int wr = wid >> 2, wc = wid & 3;      // 2 x 4 waves
  const int q = lane >> 4, j16 = lane & 15, r3 = j16 & 7;
  const int row0 = blockIdx.y << 8;           // BM = 256
  const int col0 = blockIdx.x << 8;           // BN = 256
  const int K = d.K, N = d.N, nt = K >> 6;

  // staging constants (2 gload_lds per half-tile per thread; linear LDS dest,
  // pre-swizzled global source column)
  const int rbase = (wid << 3) + (lane >> 3);                 // 0..63
  const int csw   = ((lane & 7) ^ ((lane >> 3) & 7)) << 3;    // swizzled chunk (shorts)
  const unsigned short* Ag = d.A + (size_t)row0 * K;
  const unsigned short* Bg = d.W + (size_t)col0 * K;
  const int ldst = wid << 9;                                  // wid*512 shorts

#define STAGE_A(buf_, h_, k0_) do { \
  unsigned short* slot_ = Alds + (((buf_) << 1) + (h_)) * HALF_SH; \
  _Pragma("unroll") \
  for (int i_ = 0; i_ < 2; ++i_) \
    gload_lds16(Ag + (size_t)(((h_) << 7) + (i_ << 6) + rbase) * K + (k0_) + csw, \
                slot_ + (i_ << 12) + ldst); \
} while (0)
#define STAGE_B(buf_, v_, k0_) do { \
  unsigned short* slot_ = Blds + (((buf_) << 1) + (v_)) * HALF_SH; \
  _Pragma("unroll") \
  for (int i_ = 0; i_ < 2; ++i_) \
    gload_lds16(Bg + (size_t)(((v_) << 7) + (i_ << 6) + rbase) * K + (k0_) + csw, \
                slot_ + (i_ << 12) + ldst); \
} while (0)

  // LDS read offsets (shorts), loop-invariant; swizzled to match staging
  int aoff[4][2], boff[2][2];
#pragma unroll
  for (int m = 0; m < 4; ++m)
#pragma unroll
    for (int ks = 0; ks < 2; ++ks)
      aoff[m][ks] = (wr * 64 + m * 16 + j16) * 64 + (((ks * 4 + q) ^ r3) << 3);
#pragma unroll
  for (int n = 0; n < 2; ++n)
#pragma unroll
    for (int ks = 0; ks < 2; ++ks)
      boff[n][ks] = (wc * 32 + n * 16 + j16) * 64 + (((ks * 4 + q) ^ r3) << 3);

  f32x4 acc[8][4];
#pragma unroll
  for (int m = 0; m < 8; ++m)
#pragma unroll
    for (int n = 0; n < 4; ++n) acc[m][n] = (f32x4){0.f, 0.f, 0.f, 0.f};

  bf16x8 av[2][4], bv0[2][2], bv1[2][2];

#define LDA(slot_) do { \
  _Pragma("unroll") \
  for (int ks_ = 0; ks_ < 2; ++ks_) \
    _Pragma("unroll") \
    for (int m_ = 0; m_ < 4; ++m_) \
      av[ks_][m_] = *(const bf16x8*)((slot_) + aoff[m_][ks_]); \
} while (0)
#define LDB(dst_, slot_) do { \
  _Pragma("unroll") \
  for (int ks_ = 0; ks_ < 2; ++ks_) \
    _Pragma("unroll") \
    for (int n_ = 0; n_ < 2; ++n_) \
      dst_[ks_][n_] = *(const bf16x8*)((slot_) + boff[n_][ks_]); \
} while (0)
#define MM(bvv_, mb_, nb_) do { \
  __builtin_amdgcn_s_setprio(1); \
  _Pragma("unroll") \
  for (int ks_ = 0; ks_ < 2; ++ks_) \
    _Pragma("unroll") \
    for (int m_ = 0; m_ < 4; ++m_) \
      _Pragma("unroll") \
      for (int n_ = 0; n_ < 2; ++n_) \
        acc[(mb_) + m_][(nb_) + n_] = __builtin_amdgcn_mfma_f32_16x16x32_bf16( \
            av[ks_][m_], bvv_[ks_][n_], acc[(mb_) + m_][(nb_) + n_], 0, 0, 0); \
  __builtin_amdgcn_s_setprio(0); \
} while (0)
#define GATE4 asm volatile("s_waitcnt vmcnt(4)" ::: "memory")

  // prologue: tile 0's halves into buf 0, in consumption order A0,B0,B1,A1
  STAGE_A(0, 0, 0);
  STAGE_B(0, 0, 0);
  STAGE_B(0, 1, 0);
  STAGE_A(0, 1, 0);

  for (int t = 0; t < nt; ++t) {
    const int buf = t & 1, nbuf = buf ^ 1;
    const int kn = (t + 1 < nt) ? ((t + 1) << 6) : 0;   // dummy wrap-stage on last tile
    const unsigned short* As0 = Alds + ((buf << 1) + 0) * HALF_SH;
    const unsigned short* As1 = Alds + ((buf << 1) + 1) * HALF_SH;
    const unsigned short* Bs0 = Blds + ((buf << 1) + 0) * HALF_SH;
    const unsigned short* Bs1 = Blds + ((buf << 1) + 1) * HALF_SH;

    // phase 0: (h0,v0) — gate lands A0,B0(t); stages A0(t+1)
    GATE4;
    __builtin_amdgcn_s_barrier();
    LDA(As0);
    LDB(bv0, Bs0);
    STAGE_A(nbuf, 0, kn);
    MM(bv0, 0, 0);
    // phase 1: (h0,v1) — gate lands B1(t); av held; stages B0(t+1)
    GATE4;
    __builtin_amdgcn_s_barrier();
    LDB(bv1, Bs1);
    STAGE_B(nbuf, 0, kn);
    MM(bv1, 0, 2);
    // phase 2: (h1,v1) — gate lands A1(t); bv1 held; stages B1(t+1)
    GATE4;
    __builtin_amdgcn_s_barrier();
    LDA(As1);
    STAGE_B(nbuf, 1, kn);
    MM(bv1, 4, 2);
    // phase 3: (h1,v0) — no reads, no gate; bv0/av held; stages A1(t+1)
    __builtin_amdgcn_s_barrier();
    STAGE_A(nbuf, 1, kn);
    MM(bv0, 4, 0);
  }
  asm volatile("s_waitcnt vmcnt(0)" ::: "memory");   // drain dummy tail stages

  // epilogue: per frag (m,n): h=m>>2, v=n>>1; D row=(lane>>4)*4+j, col=lane&15
#define IDX (size_t)(row0 + ((m >> 2) << 7) + wr * 64 + (m & 3) * 16 + (q << 2) + j) * N \
          + (col0 + ((n >> 1) << 7) + wc * 32 + (n & 1) * 16 + j16)
  if (d.mode == M_ACT) {
#pragma unroll
    for (int m = 0; m < 8; ++m)
#pragma unroll
      for (int n = 0; n < 4; ++n)
#pragma unroll
        for (int j = 0; j < 4; ++j) {
          const size_t idx = IDX;
          float t = fast_tanh(acc[m][n][j]);
          d.o0[idx] = f2bf(t);
          d.o1[idx] = f2bf(fmaxf(t, 0.f));
        }
  } else if (d.mode == M_ACTD) {
#pragma unroll
    for (int m = 0; m < 8; ++m)
#pragma unroll
      for (int n = 0; n < 4; ++n)
#pragma unroll
        for (int j = 0; j < 4; ++j) {
          const size_t idx = IDX;
          float t = fast_tanh(acc[m][n][j]);
          d.o0[idx] = f2bf(t);
          d.o1[idx] = f2bf(fmaxf(t, 0.f));
          d.o2[idx] = f2bf(t >= 0.f ? 0.f : (-t) * (1.f - t * t));
        }
  } else if (d.mode == M_SIG) {
#pragma unroll
    for (int m = 0; m < 8; ++m)
#pragma unroll
      for (int n = 0; n < 4; ++n)
#pragma unroll
        for (int j = 0; j < 4; ++j) {
          const size_t idx = IDX;
          float s = fast_sig(acc[m][n][j]);
          d.fout[idx] = s;
          d.o0[idx] = f2bf((d.targ[idx] - s) * s * (1.f - s));
        }
  } else if (d.mode == M_ERR) {
#pragma unroll
    for (int m = 0; m < 8; ++m)
#pragma unroll
      for (int n = 0; n < 4; ++n)
#pragma unroll
        for (int j = 0; j < 4; ++j) {
          const size_t idx = IDX;
          float a = bf2f(d.o0[idx]);
          float tp = bf2f(d.i0[idx]);
          d.o0[idx] = f2bf(fmaxf(a + 0.1f * acc[m][n][j] - 0.1f * (a - tp), 0.f));
        }
  } else {  // M_PRED
#pragma unroll
    for (int m = 0; m < 8; ++m)
#pragma unroll
      for (int n = 0; n < 4; ++n)
#pragma unroll
        for (int j = 0; j < 4; ++j) {
          const size_t idx = IDX;
          float t = fast_tanh(acc[m][n][j]);
          d.o0[idx] = f2bf(t);
          float an = bf2f(d.i0[idx]);
          d.o1[idx] = f2bf((an - t) * (1.f - t * t));
        }
  }
#undef IDX
}

// ---------------- batched f32 -> bf16 conversion (8 jobs, one launch) ----------
struct CvtJobs {
  const float* src[8];
  unsigned short* dst[8];
  int n4[8];
};
__global__ void k_cvt8(CvtJobs J) {
  const int jb = blockIdx.y;
  const float* s = J.src[jb];
  unsigned short* dd = J.dst[jb];
  const int n4 = J.n4[jb];
  int i = blockIdx.x * blockDim.x + threadIdx.x, st = gridDim.x * blockDim.x;
  for (; i < n4; i += st) {
    float4 v = ((const float4*)s)[i];
    ushort4 o; o.x = f2bf(v.x); o.y = f2bf(v.y); o.z = f2bf(v.z); o.w = f2bf(v.w);
    ((ushort4*)dd)[i] = o;
  }
}

// ------------------------------------------------------------------------------------
extern "C" void kernel_launch(void* const* d_in, const int* in_sizes, int n_in,
                              void* d_out, int out_size, void* d_ws, size_t ws_size,
                              hipStream_t stream) {
  (void)in_sizes; (void)n_in; (void)out_size; (void)ws_size;
  const float* x      = (const float*)d_in[0];
  const float* target = (const float*)d_in[1];
  const float* wSrc[7] = {(const float*)d_in[2], (const float*)d_in[3],
                          (const float*)d_in[4], (const float*)d_in[5],
                          (const float*)d_in[6], (const float*)d_in[7],
                          (const float*)d_in[8]};
  const size_t wN[7] = {(size_t)4096 * 1024, (size_t)4096 * 4096, (size_t)4096 * 4096,
                        (size_t)1024 * 4096, (size_t)4096 * 4096, (size_t)4096 * 4096,
                        (size_t)4096 * 1024};

  char* w = (char*)d_ws;
  size_t off = 0;
  auto alloc = [&](size_t bytes) { void* p = w + off; off += bytes; return p; };

  const size_t BIG = (size_t)B_ * 4096;
  const size_t SML = (size_t)B_ * 1024;
  unsigned short* xb  = (unsigned short*)alloc(SML * 2);
  unsigned short* a1b = (unsigned short*)alloc(BIG * 2);
  unsigned short* a2b = (unsigned short*)alloc(BIG * 2);
  unsigned short* a3b = (unsigned short*)alloc(BIG * 2);
  unsigned short* t0b = (unsigned short*)alloc(BIG * 2);
  unsigned short* t1b = (unsigned short*)alloc(BIG * 2);
  unsigned short* t2b = (unsigned short*)alloc(BIG * 2);
  unsigned short* d1b = (unsigned short*)alloc(BIG * 2);
  unsigned short* d2b = (unsigned short*)alloc(BIG * 2);
  unsigned short* d3b = (unsigned short*)alloc(SML * 2);
  unsigned short* Wb[7];
  for (int i = 0; i < 7; ++i) Wb[i] = (unsigned short*)alloc(wN[i] * 2);

  // ---- conversions: one batched launch ----
  CvtJobs J;
  for (int i = 0; i < 7; ++i) { J.src[i] = wSrc[i]; J.dst[i] = Wb[i]; J.n4[i] = (int)(wN[i] >> 2); }
  J.src[7] = x; J.dst[7] = xb; J.n4[7] = (int)(SML >> 2);
  k_cvt8<<<dim3(2048, 8), 256, 0, stream>>>(J);

  float* out = (float*)d_out;
  auto desc = [&](const unsigned short* A, const unsigned short* W_, int K, int N, int nx,
                  int mode, unsigned short* o0, unsigned short* o1, unsigned short* o2,
                  const unsigned short* i0, const float* targ, float* fout) {
    GDesc g; g.A = A; g.W = W_; g.o0 = o0; g.o1 = o1; g.o2 = o2; g.i0 = i0;
    g.targ = targ; g.fout = fout; g.K = K; g.N = N; g.nx = nx; g.mode = mode;
    return g;
  };

  // ---- initial feedforward (d1,d2 fused into g1/g2 epilogues) ----
  {
    GDesc g0 = desc(xb,  Wb[0], 1024, 4096, 16, M_ACT,  t0b, a1b, nullptr, nullptr, nullptr, nullptr);
    gemm8p<<<dim3(16, 8, 1), 512, LDS_BYTES, stream>>>(g0, g0, g0);
    GDesc g1 = desc(a1b, Wb[1], 4096, 4096, 16, M_ACTD, t1b, a2b, d1b, nullptr, nullptr, nullptr);
    gemm8p<<<dim3(16, 8, 1), 512, LDS_BYTES, stream>>>(g1, g1, g1);
    GDesc g2 = desc(a2b, Wb[2], 4096, 4096, 16, M_ACTD, t2b, a3b, d2b, nullptr, nullptr, nullptr);
    gemm8p<<<dim3(16, 8, 1), 512, LDS_BYTES, stream>>>(g2, g2, g2);
    GDesc g3 = desc(a3b, Wb[3], 4096, 1024, 4,  M_SIG,  d3b, nullptr, nullptr, nullptr, target, out);
    gemm8p<<<dim3(4, 8, 1), 512, LDS_BYTES, stream>>>(g3, g3, g3);
  }

  // ---- 5 inference iterations: 2 batched launches each ----
  for (int it = 0; it < 5; ++it) {
    GDesc e0 = desc(d1b, Wb[4], 4096, 4096, 16, M_ERR, a1b, nullptr, nullptr, t0b, nullptr, nullptr);
    GDesc e1 = desc(d2b, Wb[5], 4096, 4096, 16, M_ERR, a2b, nullptr, nullptr, t1b, nullptr, nullptr);
    GDesc e2 = desc(d3b, Wb[6], 1024, 4096, 16, M_ERR, a3b, nullptr, nullptr, t2b, nullptr, nullptr);
    gemm8p<<<dim3(16, 8, 3), 512, LDS_BYTES, stream>>>(e0, e1, e2);
    GDesc p0 = desc(a1b, Wb[1], 4096, 4096, 16, M_PRED, t1b, d1b, nullptr, a2b, nullptr, nullptr);
    GDesc p1 = desc(a2b, Wb[2], 4096, 4096, 16, M_PRED, t2b, d2b, nullptr, a3b, nullptr, nullptr);
    GDesc p2 = desc(a3b, Wb[3], 4096, 1024, 4,  M_SIG,  d3b, nullptr, nullptr, nullptr, target, out);
    gemm8p<<<dim3(16, 8, 3), 512, LDS_BYTES, stream>>>(p0, p1, p2);
  }
}

// Round 7
// 2494.874 us; speedup vs baseline: 1.0734x; 1.0312x over previous
//
#include <hip/hip_runtime.h>
#include <stdint.h>

// Predictive-coding inference: LAYER_SZS=[1024,4096,4096,4096,1024], B=2048, 5 iters.
// GEMM: C[M,N] = A[M,K](bf16) @ W[N,K](bf16)^T, f32 accum, fused epilogues.
// 256x256 tile, BK=64, 8 waves (2x4), per-wave 128x64 out, 2-deep half-tile dbuf.
// Pipelined K-tile: ONE vmcnt(0)+barrier per tile, then 24 ds_read_b128 (all four
// register sets), then 8 global_load_lds staging tile t+1, then 64 MFMA in 4
// setprio'd quadrant clusters -- LDS pipe overlaps MFMA pipe, waits are
// compiler-counted lgkmcnt. XOR bank-swizzle both-sides (conflicts = 0, r4).
// Split-K partials for N=1024 legs (tail shaping) + XCD-bijective block swizzle.

typedef __attribute__((ext_vector_type(8))) __bf16 bf16x8;
typedef __attribute__((ext_vector_type(4))) float f32x4;

#define B_ 2048
#define HALF_SH 8192                 // shorts per half-tile (128 rows x 64 cols)
#define LDS_BYTES (8 * HALF_SH * 2)  // 131072

__device__ __forceinline__ unsigned short f2bf(float f) {
  union { float f; unsigned u; } v; v.f = f;
  unsigned u = v.u;
  u += 0x7FFFu + ((u >> 16) & 1u);
  return (unsigned short)(u >> 16);
}
__device__ __forceinline__ float bf2f(unsigned short s) {
  union { unsigned u; float f; } v; v.u = ((unsigned)s) << 16;
  return v.f;
}
__device__ __forceinline__ float fast_sig(float x) { return 1.0f / (1.0f + __expf(-x)); }
__device__ __forceinline__ float fast_tanh(float x) {
  return 1.0f - 2.0f / (__expf(2.0f * x) + 1.0f);
}
__device__ __forceinline__ void gload_lds16(const void* g, void* l) {
  __builtin_amdgcn_global_load_lds((const __attribute__((address_space(1))) void*)g,
                                   (__attribute__((address_space(3))) void*)l, 16, 0, 0);
}

// epilogue modes
#define M_ACT  0   // o0=t=tanh(acc); o1=relu(t)
#define M_ACTD 1   // + o2 = d = (relu(t)-t)(1-t^2)
#define M_SIG  2   // s=sig(acc); o0=(targ-s)s(1-s); fout=s
#define M_ERR  3   // o0(a) = relu(a + 0.1*acc - 0.1*(a - i0))
#define M_PRED 4   // t=tanh(acc); o0=t; o1=(i0 - t)(1-t^2)
#define M_PART 5   // fout[sk-plane] = acc (f32 partial sums, split-K)

struct GDesc {
  const unsigned short* A;   // [M,K]
  const unsigned short* W;   // [N,K]
  unsigned short* o0;
  unsigned short* o1;
  unsigned short* o2;
  const unsigned short* i0;
  const float* targ;
  float* fout;
  int K;     // row stride (elements)
  int knt;   // K-tiles (BK=64) per block
  int N, nx, mode;
};

__global__ __launch_bounds__(512, 2) void gemm8p(GDesc d0, GDesc d1, GDesc d2) {
  const GDesc d = (blockIdx.z == 0) ? d0 : (blockIdx.z == 1 ? d1 : d2);

  extern __shared__ __attribute__((aligned(16))) unsigned short lds[];
  unsigned short* Alds = lds;                 // [buf][h] x HALF_SH
  unsigned short* Blds = lds + 4 * HALF_SH;   // [buf][v] x HALF_SH

  const int tid = threadIdx.x;
  const int wid = tid >> 6, lane = tid & 63;
  const int wr = wid >> 2, wc = wid & 3;      // 2 x 4 waves
  const int q = lane >> 4, j16 = lane & 15, r3 = j16 & 7;
  const int K = d.K, N = d.N, nt = d.knt, nx = d.nx;

  // XCD-bijective swizzle within the (x, y&7) plane (nwg = nx*8, nwg%8==0)
  const int sk  = blockIdx.y >> 3;            // split-K index (0 unless split)
  const int cpx = nx;                         // nwg/8 = nx
  const int lid = (blockIdx.y & 7) * nx + blockIdx.x;
  const int swz = (lid & 7) * cpx + (lid >> 3);
  const int bx  = swz % nx, my = swz / nx;
  const int row0 = my << 8;                   // BM = 256
  const int col0 = bx << 8;                   // BN = 256
  const int kbeg = (sk * nt) << 6;

  // staging constants (2 gload_lds per half-tile per thread; linear LDS dest,
  // pre-swizzled global source column)
  const int rbase = (wid << 3) + (lane >> 3);                 // 0..63
  const int csw   = ((lane & 7) ^ ((lane >> 3) & 7)) << 3;    // swizzled chunk (shorts)
  const unsigned short* Ag = d.A + (size_t)row0 * K;
  const unsigned short* Bg = d.W + (size_t)col0 * K;
  const int ldst = wid << 9;                                  // wid*512 shorts

#define STAGE_A(buf_, h_, k0_) do { \
  unsigned short* slot_ = Alds + (((buf_) << 1) + (h_)) * HALF_SH; \
  _Pragma("unroll") \
  for (int i_ = 0; i_ < 2; ++i_) \
    gload_lds16(Ag + (size_t)(((h_) << 7) + (i_ << 6) + rbase) * K + (k0_) + csw, \
                slot_ + (i_ << 12) + ldst); \
} while (0)
#define STAGE_B(buf_, v_, k0_) do { \
  unsigned short* slot_ = Blds + (((buf_) << 1) + (v_)) * HALF_SH; \
  _Pragma("unroll") \
  for (int i_ = 0; i_ < 2; ++i_) \
    gload_lds16(Bg + (size_t)(((v_) << 7) + (i_ << 6) + rbase) * K + (k0_) + csw, \
                slot_ + (i_ << 12) + ldst); \
} while (0)

  // LDS read offsets (shorts), loop-invariant; swizzled to match staging
  int aoff[4][2], boff[2][2];
#pragma unroll
  for (int m = 0; m < 4; ++m)
#pragma unroll
    for (int ks = 0; ks < 2; ++ks)
      aoff[m][ks] = (wr * 64 + m * 16 + j16) * 64 + (((ks * 4 + q) ^ r3) << 3);
#pragma unroll
  for (int n = 0; n < 2; ++n)
#pragma unroll
    for (int ks = 0; ks < 2; ++ks)
      boff[n][ks] = (wc * 32 + n * 16 + j16) * 64 + (((ks * 4 + q) ^ r3) << 3);

  f32x4 acc[8][4];
#pragma unroll
  for (int m = 0; m < 8; ++m)
#pragma unroll
    for (int n = 0; n < 4; ++n) acc[m][n] = (f32x4){0.f, 0.f, 0.f, 0.f};

  bf16x8 av0[2][4], av1[2][4], bv0[2][2], bv1[2][2];

#define LDA(dst_, slot_) do { \
  _Pragma("unroll") \
  for (int ks_ = 0; ks_ < 2; ++ks_) \
    _Pragma("unroll") \
    for (int m_ = 0; m_ < 4; ++m_) \
      dst_[ks_][m_] = *(const bf16x8*)((slot_) + aoff[m_][ks_]); \
} while (0)
#define LDB(dst_, slot_) do { \
  _Pragma("unroll") \
  for (int ks_ = 0; ks_ < 2; ++ks_) \
    _Pragma("unroll") \
    for (int n_ = 0; n_ < 2; ++n_) \
      dst_[ks_][n_] = *(const bf16x8*)((slot_) + boff[n_][ks_]); \
} while (0)
#define MM(avv_, bvv_, mb_, nb_) do { \
  __builtin_amdgcn_s_setprio(1); \
  _Pragma("unroll") \
  for (int ks_ = 0; ks_ < 2; ++ks_) \
    _Pragma("unroll") \
    for (int m_ = 0; m_ < 4; ++m_) \
      _Pragma("unroll") \
      for (int n_ = 0; n_ < 2; ++n_) \
        acc[(mb_) + m_][(nb_) + n_] = __builtin_amdgcn_mfma_f32_16x16x32_bf16( \
            avv_[ks_][m_], bvv_[ks_][n_], acc[(mb_) + m_][(nb_) + n_], 0, 0, 0); \
  __builtin_amdgcn_s_setprio(0); \
} while (0)

  // prologue: tile 0's four halves into buf 0
  STAGE_A(0, 0, kbeg);
  STAGE_B(0, 0, kbeg);
  STAGE_B(0, 1, kbeg);
  STAGE_A(0, 1, kbeg);

  for (int t = 0; t < nt; ++t) {
    const int buf = t & 1, nbuf = buf ^ 1;
    const unsigned short* As0 = Alds + ((buf << 1) + 0) * HALF_SH;
    const unsigned short* As1 = Alds + ((buf << 1) + 1) * HALF_SH;
    const unsigned short* Bs0 = Blds + ((buf << 1) + 0) * HALF_SH;
    const unsigned short* Bs1 = Blds + ((buf << 1) + 1) * HALF_SH;

    // gate: tile t fully landed (its 8 stage ops are the only outstanding vmem)
    asm volatile("s_waitcnt vmcnt(0)" ::: "memory");
    __builtin_amdgcn_s_barrier();

    // all 24 ds_reads up front -- LDS pipe fills while MFMA clusters drain it.
    LDA(av0, As0);
    LDB(bv0, Bs0);
    LDB(bv1, Bs1);
    LDA(av1, As1);

    // stage tile t+1 (writes nbuf; no reg deps, vmcnt-tracked only)
    if (t + 1 < nt) {
      const int kn = kbeg + ((t + 1) << 6);
      STAGE_A(nbuf, 0, kn);
      STAGE_B(nbuf, 0, kn);
      STAGE_B(nbuf, 1, kn);
      STAGE_A(nbuf, 1, kn);
    }

    // 4 quadrant clusters; compiler inserts counted lgkmcnt per cluster
    MM(av0, bv0, 0, 0);
    MM(av0, bv1, 0, 2);
    MM(av1, bv1, 4, 2);
    MM(av1, bv0, 4, 0);
  }

  // epilogue: per frag (m,n): h=m>>2, v=n>>1; D row=(lane>>4)*4+j, col=lane&15
#define IDX (size_t)(row0 + ((m >> 2) << 7) + wr * 64 + (m & 3) * 16 + (q << 2) + j) * N \
          + (col0 + ((n >> 1) << 7) + wc * 32 + (n & 1) * 16 + j16)
  if (d.mode == M_ACT) {
#pragma unroll
    for (int m = 0; m < 8; ++m)
#pragma unroll
      for (int n = 0; n < 4; ++n)
#pragma unroll
        for (int j = 0; j < 4; ++j) {
          const size_t idx = IDX;
          float t = fast_tanh(acc[m][n][j]);
          d.o0[idx] = f2bf(t);
          d.o1[idx] = f2bf(fmaxf(t, 0.f));
        }
  } else if (d.mode == M_ACTD) {
#pragma unroll
    for (int m = 0; m < 8; ++m)
#pragma unroll
      for (int n = 0; n < 4; ++n)
#pragma unroll
        for (int j = 0; j < 4; ++j) {
          const size_t idx = IDX;
          float t = fast_tanh(acc[m][n][j]);
          d.o0[idx] = f2bf(t);
          d.o1[idx] = f2bf(fmaxf(t, 0.f));
          d.o2[idx] = f2bf(t >= 0.f ? 0.f : (-t) * (1.f - t * t));
        }
  } else if (d.mode == M_SIG) {
#pragma unroll
    for (int m = 0; m < 8; ++m)
#pragma unroll
      for (int n = 0; n < 4; ++n)
#pragma unroll
        for (int j = 0; j < 4; ++j) {
          const size_t idx = IDX;
          float s = fast_sig(acc[m][n][j]);
          d.fout[idx] = s;
          d.o0[idx] = f2bf((d.targ[idx] - s) * s * (1.f - s));
        }
  } else if (d.mode == M_ERR) {
#pragma unroll
    for (int m = 0; m < 8; ++m)
#pragma unroll
      for (int n = 0; n < 4; ++n)
#pragma unroll
        for (int j = 0; j < 4; ++j) {
          const size_t idx = IDX;
          float a = bf2f(d.o0[idx]);
          float tp = bf2f(d.i0[idx]);
          d.o0[idx] = f2bf(fmaxf(a + 0.1f * acc[m][n][j] - 0.1f * (a - tp), 0.f));
        }
  } else if (d.mode == M_PRED) {
#pragma unroll
    for (int m = 0; m < 8; ++m)
#pragma unroll
      for (int n = 0; n < 4; ++n)
#pragma unroll
        for (int j = 0; j < 4; ++j) {
          const size_t idx = IDX;
          float t = fast_tanh(acc[m][n][j]);
          d.o0[idx] = f2bf(t);
          float an = bf2f(d.i0[idx]);
          d.o1[idx] = f2bf((an - t) * (1.f - t * t));
        }
  } else {  // M_PART: f32 partial sums, one plane per split
    float* po = d.fout + (size_t)sk * 2048 * N;
#pragma unroll
    for (int m = 0; m < 8; ++m)
#pragma unroll
      for (int n = 0; n < 4; ++n)
#pragma unroll
        for (int j = 0; j < 4; ++j) {
          const size_t idx = IDX;
          po[idx] = acc[m][n][j];
        }
  }
#undef IDX
}

// ---------------- split-K combine: sum partials -> sigmoid -> d3, out ----------
__global__ void k_comb(const float* __restrict__ psum, const float* __restrict__ targ,
                       unsigned short* __restrict__ d3, float* __restrict__ out,
                       int n4, int ks) {
  const size_t plane4 = (size_t)2048 * 1024 / 4;
  int i = blockIdx.x * blockDim.x + threadIdx.x, st = gridDim.x * blockDim.x;
  for (; i < n4; i += st) {
    float4 s0 = ((const float4*)psum)[i];
    for (int s = 1; s < ks; ++s) {
      float4 sv = ((const float4*)psum)[i + s * plane4];
      s0.x += sv.x; s0.y += sv.y; s0.z += sv.z; s0.w += sv.w;
    }
    float4 tv = ((const float4*)targ)[i];
    float4 o; ushort4 dv; float sg;
    sg = fast_sig(s0.x); o.x = sg; dv.x = f2bf((tv.x - sg) * sg * (1.f - sg));
    sg = fast_sig(s0.y); o.y = sg; dv.y = f2bf((tv.y - sg) * sg * (1.f - sg));
    sg = fast_sig(s0.z); o.z = sg; dv.z = f2bf((tv.z - sg) * sg * (1.f - sg));
    sg = fast_sig(s0.w); o.w = sg; dv.w = f2bf((tv.w - sg) * sg * (1.f - sg));
    ((float4*)out)[i] = o;
    ((ushort4*)d3)[i] = dv;
  }
}

// ---------------- batched f32 -> bf16 conversion (8 jobs, one launch) ----------
struct CvtJobs {
  const float* src[8];
  unsigned short* dst[8];
  int n4[8];
};
__global__ void k_cvt8(CvtJobs J) {
  const int jb = blockIdx.y;
  const float* s = J.src[jb];
  unsigned short* dd = J.dst[jb];
  const int n4 = J.n4[jb];
  int i = blockIdx.x * blockDim.x + threadIdx.x, st = gridDim.x * blockDim.x;
  for (; i < n4; i += st) {
    float4 v = ((const float4*)s)[i];
    ushort4 o; o.x = f2bf(v.x); o.y = f2bf(v.y); o.z = f2bf(v.z); o.w = f2bf(v.w);
    ((ushort4*)dd)[i] = o;
  }
}

// ------------------------------------------------------------------------------------
extern "C" void kernel_launch(void* const* d_in, const int* in_sizes, int n_in,
                              void* d_out, int out_size, void* d_ws, size_t ws_size,
                              hipStream_t stream) {
  (void)in_sizes; (void)n_in; (void)out_size;
  const float* x      = (const float*)d_in[0];
  const float* target = (const float*)d_in[1];
  const float* wSrc[7] = {(const float*)d_in[2], (const float*)d_in[3],
                          (const float*)d_in[4], (const float*)d_in[5],
                          (const float*)d_in[6], (const float*)d_in[7],
                          (const float*)d_in[8]};
  const size_t wN[7] = {(size_t)4096 * 1024, (size_t)4096 * 4096, (size_t)4096 * 4096,
                        (size_t)1024 * 4096, (size_t)4096 * 4096, (size_t)4096 * 4096,
                        (size_t)4096 * 1024};

  char* w = (char*)d_ws;
  size_t off = 0;
  auto alloc = [&](size_t bytes) { void* p = w + off; off += bytes; return p; };

  const size_t BIG = (size_t)B_ * 4096;
  const size_t SML = (size_t)B_ * 1024;
  unsigned short* xb  = (unsigned short*)alloc(SML * 2);
  unsigned short* a1b = (unsigned short*)alloc(BIG * 2);
  unsigned short* a2b = (unsigned short*)alloc(BIG * 2);
  unsigned short* a3b = (unsigned short*)alloc(BIG * 2);
  unsigned short* t0b = (unsigned short*)alloc(BIG * 2);
  unsigned short* t1b = (unsigned short*)alloc(BIG * 2);
  unsigned short* t2b = (unsigned short*)alloc(BIG * 2);
  unsigned short* d1b = (unsigned short*)alloc(BIG * 2);
  unsigned short* d2b = (unsigned short*)alloc(BIG * 2);
  unsigned short* d3b = (unsigned short*)alloc(SML * 2);
  unsigned short* Wb[7];
  for (int i = 0; i < 7; ++i) Wb[i] = (unsigned short*)alloc(wN[i] * 2);

  // split-K partials for the N=1024 legs (p2/g3): adaptive to ws_size
  const size_t PS = SML * 4;  // 8 MB per split plane (f32 2048x1024)
  int KS = 1;
  if (ws_size >= off + 4 * PS) KS = 4;
  else if (ws_size >= off + 2 * PS) KS = 2;
  float* psum = (KS > 1) ? (float*)alloc((size_t)KS * PS) : nullptr;

  // ---- conversions: one batched launch ----
  CvtJobs J;
  for (int i = 0; i < 7; ++i) { J.src[i] = wSrc[i]; J.dst[i] = Wb[i]; J.n4[i] = (int)(wN[i] >> 2); }
  J.src[7] = x; J.dst[7] = xb; J.n4[7] = (int)(SML >> 2);
  k_cvt8<<<dim3(2048, 8), 256, 0, stream>>>(J);

  float* out = (float*)d_out;
  const int n4_sml = (int)(SML >> 2);
  auto desc = [&](const unsigned short* A, const unsigned short* W_, int K, int knt,
                  int N, int nx, int mode, unsigned short* o0, unsigned short* o1,
                  unsigned short* o2, const unsigned short* i0, const float* targ,
                  float* fout) {
    GDesc g; g.A = A; g.W = W_; g.o0 = o0; g.o1 = o1; g.o2 = o2; g.i0 = i0;
    g.targ = targ; g.fout = fout; g.K = K; g.knt = knt; g.N = N; g.nx = nx; g.mode = mode;
    return g;
  };
  // p2/g3 leg: split-K partials + combine, or direct M_SIG when KS==1
  auto launch_sig_leg = [&](const unsigned short* A) {
    if (KS > 1) {
      GDesc g = desc(A, Wb[3], 4096, 64 / KS, 1024, 4, M_PART,
                     nullptr, nullptr, nullptr, nullptr, nullptr, psum);
      gemm8p<<<dim3(4, 8 * KS, 1), 512, LDS_BYTES, stream>>>(g, g, g);
      k_comb<<<2048, 256, 0, stream>>>(psum, target, d3b, out, n4_sml, KS);
    } else {
      GDesc g = desc(A, Wb[3], 4096, 64, 1024, 4, M_SIG,
                     d3b, nullptr, nullptr, nullptr, target, out);
      gemm8p<<<dim3(4, 8, 1), 512, LDS_BYTES, stream>>>(g, g, g);
    }
  };

  // ---- initial feedforward (d1,d2 fused into g1/g2 epilogues) ----
  {
    GDesc g0 = desc(xb,  Wb[0], 1024, 16, 4096, 16, M_ACT,  t0b, a1b, nullptr, nullptr, nullptr, nullptr);
    gemm8p<<<dim3(16, 8, 1), 512, LDS_BYTES, stream>>>(g0, g0, g0);
    GDesc g1 = desc(a1b, Wb[1], 4096, 64, 4096, 16, M_ACTD, t1b, a2b, d1b, nullptr, nullptr, nullptr);
    gemm8p<<<dim3(16, 8, 1), 512, LDS_BYTES, stream>>>(g1, g1, g1);
    GDesc g2 = desc(a2b, Wb[2], 4096, 64, 4096, 16, M_ACTD, t2b, a3b, d2b, nullptr, nullptr, nullptr);
    gemm8p<<<dim3(16, 8, 1), 512, LDS_BYTES, stream>>>(g2, g2, g2);
    launch_sig_leg(a3b);
  }

  // ---- 5 inference iterations ----
  for (int it = 0; it < 5; ++it) {
    // L_E: e0,e1 long (K=4096) + e2 short (K=1024) -- 384 blocks, longs first
    GDesc e0 = desc(d1b, Wb[4], 4096, 64, 4096, 16, M_ERR, a1b, nullptr, nullptr, t0b, nullptr, nullptr);
    GDesc e1 = desc(d2b, Wb[5], 4096, 64, 4096, 16, M_ERR, a2b, nullptr, nullptr, t1b, nullptr, nullptr);
    GDesc e2 = desc(d3b, Wb[6], 1024, 16, 4096, 16, M_ERR, a3b, nullptr, nullptr, t2b, nullptr, nullptr);
    gemm8p<<<dim3(16, 8, 3), 512, LDS_BYTES, stream>>>(e0, e1, e2);
    // L_P: p0,p1 -- exactly 256 blocks
    GDesc p0 = desc(a1b, Wb[1], 4096, 64, 4096, 16, M_PRED, t1b, d1b, nullptr, a2b, nullptr, nullptr);
    GDesc p1 = desc(a2b, Wb[2], 4096, 64, 4096, 16, M_PRED, t2b, d2b, nullptr, a3b, nullptr, nullptr);
    gemm8p<<<dim3(16, 8, 2), 512, LDS_BYTES, stream>>>(p0, p1, p1);
    // L_P2: p2 split-K (+combine)
    launch_sig_leg(a3b);
  }
}

// Round 8
// 2359.552 us; speedup vs baseline: 1.1350x; 1.0574x over previous
//
#include <hip/hip_runtime.h>
#include <stdint.h>

// Predictive-coding inference: LAYER_SZS=[1024,4096,4096,4096,1024], B=2048, 5 iters.
// GEMM: C[M,N] = A[M,K](bf16) @ W[N,K](bf16)^T, f32 accum, fused epilogues.
// m201-faithful 8-phase schedule: BM=BN=256, BK=64, 8 waves (2x4), per-wave 128x64.
// 2-deep half-tile dbuf (128KB LDS). Per phase: {ds_read subtile; stage 1 half
// (2 gload_lds); [lgkm(8) if 12 reads]; barrier; lgkm(0); setprio 16-MFMA; barrier}.
// vmcnt(6) ONLY at phase 4 (once per K-tile) -- counted, never 0 in loop.
// Stage order: P1->(t+1):A1, P2..P4->(t+2):A0,B0,B1; prologue t0 all + t1 x3.
// XOR bank-swizzle (0 conflicts, r4). Natural block mapping (r7 XCD remap hurt).

typedef __attribute__((ext_vector_type(8))) __bf16 bf16x8;
typedef __attribute__((ext_vector_type(4))) float f32x4;

#define B_ 2048
#define HALF_SH 8192                 // shorts per half-tile (128 rows x 64 cols)
#define LDS_BYTES (8 * HALF_SH * 2)  // 131072

__device__ __forceinline__ unsigned short f2bf(float f) {
  union { float f; unsigned u; } v; v.f = f;
  unsigned u = v.u;
  u += 0x7FFFu + ((u >> 16) & 1u);
  return (unsigned short)(u >> 16);
}
__device__ __forceinline__ float bf2f(unsigned short s) {
  union { unsigned u; float f; } v; v.u = ((unsigned)s) << 16;
  return v.f;
}
__device__ __forceinline__ float fast_sig(float x) { return 1.0f / (1.0f + __expf(-x)); }
__device__ __forceinline__ float fast_tanh(float x) {
  return 1.0f - 2.0f / (__expf(2.0f * x) + 1.0f);
}
__device__ __forceinline__ void gload_lds16(const void* g, void* l) {
  __builtin_amdgcn_global_load_lds((const __attribute__((address_space(1))) void*)g,
                                   (__attribute__((address_space(3))) void*)l, 16, 0, 0);
}

// epilogue modes
#define M_ACT  0   // o0=t=tanh(acc); o1=relu(t)
#define M_ACTD 1   // + o2 = d = (relu(t)-t)(1-t^2)
#define M_SIG  2   // s=sig(acc); o0=(targ-s)s(1-s); fout=s
#define M_ERR  3   // o0(a) = relu(a + 0.1*acc - 0.1*(a - i0))
#define M_PRED 4   // t=tanh(acc); o0=t; o1=(i0 - t)(1-t^2)
#define M_PART 5   // fout[sk-plane] = acc (f32 partial sums, split-K)

struct GDesc {
  const unsigned short* A;   // [M,K]
  const unsigned short* W;   // [N,K]
  unsigned short* o0;
  unsigned short* o1;
  unsigned short* o2;
  const unsigned short* i0;
  const float* targ;
  float* fout;
  int K;     // row stride (elements)
  int knt;   // K-tiles (BK=64) per block
  int N, mode;
};

__global__ __launch_bounds__(512, 2) void gemm8p(GDesc d0, GDesc d1, GDesc d2) {
  const GDesc d = (blockIdx.z == 0) ? d0 : (blockIdx.z == 1 ? d1 : d2);

  extern __shared__ __attribute__((aligned(16))) unsigned short lds[];
  unsigned short* Alds = lds;                 // [buf][h] x HALF_SH
  unsigned short* Blds = lds + 4 * HALF_SH;   // [buf][v] x HALF_SH

  const int tid = threadIdx.x;
  const int wid = tid >> 6, lane = tid & 63;
  const int wr = wid >> 2, wc = wid & 3;      // 2 x 4 waves
  const int q = lane >> 4, j16 = lane & 15, r3 = j16 & 7;
  const int K = d.K, N = d.N, nt = d.knt;

  const int sk  = blockIdx.y >> 3;            // split-K plane (0 unless split leg)
  const int row0 = (blockIdx.y & 7) << 8;     // BM = 256
  const int col0 = blockIdx.x << 8;           // BN = 256
  const int kbeg = (sk * nt) << 6;

  // staging constants (2 gload_lds per half-tile per thread; linear LDS dest,
  // pre-swizzled global source column)
  const int rbase = (wid << 3) + (lane >> 3);                 // 0..63
  const int csw   = ((lane & 7) ^ ((lane >> 3) & 7)) << 3;    // swizzled chunk (shorts)
  const unsigned short* Ag = d.A + (size_t)row0 * K;
  const unsigned short* Bg = d.W + (size_t)col0 * K;
  const int ldst = wid << 9;                                  // wid*512 shorts

#define STAGE_A(buf_, h_, k0_) do { \
  unsigned short* slot_ = Alds + (((buf_) << 1) + (h_)) * HALF_SH; \
  _Pragma("unroll") \
  for (int i_ = 0; i_ < 2; ++i_) \
    gload_lds16(Ag + (size_t)(((h_) << 7) + (i_ << 6) + rbase) * K + (k0_) + csw, \
                slot_ + (i_ << 12) + ldst); \
} while (0)
#define STAGE_B(buf_, v_, k0_) do { \
  unsigned short* slot_ = Blds + (((buf_) << 1) + (v_)) * HALF_SH; \
  _Pragma("unroll") \
  for (int i_ = 0; i_ < 2; ++i_) \
    gload_lds16(Bg + (size_t)(((v_) << 7) + (i_ << 6) + rbase) * K + (k0_) + csw, \
                slot_ + (i_ << 12) + ldst); \
} while (0)

  // LDS read offsets (shorts), loop-invariant; swizzled to match staging
  int aoff[4][2], boff[2][2];
#pragma unroll
  for (int m = 0; m < 4; ++m)
#pragma unroll
    for (int ks = 0; ks < 2; ++ks)
      aoff[m][ks] = (wr * 64 + m * 16 + j16) * 64 + (((ks * 4 + q) ^ r3) << 3);
#pragma unroll
  for (int n = 0; n < 2; ++n)
#pragma unroll
    for (int ks = 0; ks < 2; ++ks)
      boff[n][ks] = (wc * 32 + n * 16 + j16) * 64 + (((ks * 4 + q) ^ r3) << 3);

  f32x4 acc[8][4];
#pragma unroll
  for (int m = 0; m < 8; ++m)
#pragma unroll
    for (int n = 0; n < 4; ++n) acc[m][n] = (f32x4){0.f, 0.f, 0.f, 0.f};

  bf16x8 av0[2][4], av1[2][4], bv0[2][2], bv1[2][2];

#define LDA(dst_, slot_) do { \
  _Pragma("unroll") \
  for (int ks_ = 0; ks_ < 2; ++ks_) \
    _Pragma("unroll") \
    for (int m_ = 0; m_ < 4; ++m_) \
      dst_[ks_][m_] = *(const bf16x8*)((slot_) + aoff[m_][ks_]); \
} while (0)
#define LDB(dst_, slot_) do { \
  _Pragma("unroll") \
  for (int ks_ = 0; ks_ < 2; ++ks_) \
    _Pragma("unroll") \
    for (int n_ = 0; n_ < 2; ++n_) \
      dst_[ks_][n_] = *(const bf16x8*)((slot_) + boff[n_][ks_]); \
} while (0)
#define MM(avv_, bvv_, mb_, nb_) do { \
  __builtin_amdgcn_s_setprio(1); \
  _Pragma("unroll") \
  for (int ks_ = 0; ks_ < 2; ++ks_) \
    _Pragma("unroll") \
    for (int m_ = 0; m_ < 4; ++m_) \
      _Pragma("unroll") \
      for (int n_ = 0; n_ < 2; ++n_) \
        acc[(mb_) + m_][(nb_) + n_] = __builtin_amdgcn_mfma_f32_16x16x32_bf16( \
            avv_[ks_][m_], bvv_[ks_][n_], acc[(mb_) + m_][(nb_) + n_], 0, 0, 0); \
  __builtin_amdgcn_s_setprio(0); \
} while (0)
#define BAR __builtin_amdgcn_s_barrier()
#define LGKM0 asm volatile("s_waitcnt lgkmcnt(0)" ::: "memory")

  // prologue: t0 all 4 halves + t1 first 3 halves; vmcnt(6) => t0 resident
  STAGE_A(0, 0, kbeg);
  STAGE_B(0, 0, kbeg);
  STAGE_B(0, 1, kbeg);
  STAGE_A(0, 1, kbeg);
  {
    const int k1 = kbeg + ((1 < nt ? 1 : 0) << 6);
    STAGE_A(1, 0, k1);
    STAGE_B(1, 0, k1);
    STAGE_B(1, 1, k1);
  }
  asm volatile("s_waitcnt vmcnt(6)" ::: "memory");
  BAR;

  for (int t = 0; t < nt; ++t) {
    const int buf = t & 1;
    const int b1 = (t + 1) & 1, b2 = t & 1;
    const int k1 = kbeg + (((t + 1) < nt ? (t + 1) : 0) << 6);
    const int k2 = kbeg + (((t + 2) < nt ? (t + 2) : 0) << 6);
    const unsigned short* As0 = Alds + ((buf << 1) + 0) * HALF_SH;
    const unsigned short* As1 = Alds + ((buf << 1) + 1) * HALF_SH;
    const unsigned short* Bs0 = Blds + ((buf << 1) + 0) * HALF_SH;
    const unsigned short* Bs1 = Blds + ((buf << 1) + 1) * HALF_SH;

    // P1: reads av0,bv0 (12); stages (t+1):A1
    LDA(av0, As0);
    LDB(bv0, Bs0);
    STAGE_A(b1, 1, k1);
    asm volatile("s_waitcnt lgkmcnt(8)" ::: "memory");
    BAR;
    LGKM0;
    MM(av0, bv0, 0, 0);
    BAR;
    // P2: reads bv1 (4); stages (t+2):A0
    LDB(bv1, Bs1);
    STAGE_A(b2, 0, k2);
    BAR;
    LGKM0;
    MM(av0, bv1, 0, 2);
    BAR;
    // P3: reads av1 (8); stages (t+2):B0
    LDA(av1, As1);
    STAGE_B(b2, 0, k2);
    BAR;
    LGKM0;
    MM(av1, bv1, 4, 2);
    BAR;
    // P4: no reads; stages (t+2):B1; counted vmcnt(6) => tile t+1 resident
    STAGE_B(b2, 1, k2);
    asm volatile("s_waitcnt vmcnt(6)" ::: "memory");
    BAR;
    MM(av1, bv0, 4, 0);
    BAR;
  }
  asm volatile("s_waitcnt vmcnt(0)" ::: "memory");  // drain dummy tail stages
  BAR;

  // epilogue: per frag (m,n): h=m>>2, v=n>>1; D row=(lane>>4)*4+j, col=lane&15
#define IDX (size_t)(row0 + ((m >> 2) << 7) + wr * 64 + (m & 3) * 16 + (q << 2) + j) * N \
          + (col0 + ((n >> 1) << 7) + wc * 32 + (n & 1) * 16 + j16)
  if (d.mode == M_ACT) {
#pragma unroll
    for (int m = 0; m < 8; ++m)
#pragma unroll
      for (int n = 0; n < 4; ++n)
#pragma unroll
        for (int j = 0; j < 4; ++j) {
          const size_t idx = IDX;
          float t = fast_tanh(acc[m][n][j]);
          d.o0[idx] = f2bf(t);
          d.o1[idx] = f2bf(fmaxf(t, 0.f));
        }
  } else if (d.mode == M_ACTD) {
#pragma unroll
    for (int m = 0; m < 8; ++m)
#pragma unroll
      for (int n = 0; n < 4; ++n)
#pragma unroll
        for (int j = 0; j < 4; ++j) {
          const size_t idx = IDX;
          float t = fast_tanh(acc[m][n][j]);
          d.o0[idx] = f2bf(t);
          d.o1[idx] = f2bf(fmaxf(t, 0.f));
          d.o2[idx] = f2bf(t >= 0.f ? 0.f : (-t) * (1.f - t * t));
        }
  } else if (d.mode == M_SIG) {
#pragma unroll
    for (int m = 0; m < 8; ++m)
#pragma unroll
      for (int n = 0; n < 4; ++n)
#pragma unroll
        for (int j = 0; j < 4; ++j) {
          const size_t idx = IDX;
          float s = fast_sig(acc[m][n][j]);
          d.fout[idx] = s;
          d.o0[idx] = f2bf((d.targ[idx] - s) * s * (1.f - s));
        }
  } else if (d.mode == M_ERR) {
#pragma unroll
    for (int m = 0; m < 8; ++m)
#pragma unroll
      for (int n = 0; n < 4; ++n)
#pragma unroll
        for (int j = 0; j < 4; ++j) {
          const size_t idx = IDX;
          float a = bf2f(d.o0[idx]);
          float tp = bf2f(d.i0[idx]);
          d.o0[idx] = f2bf(fmaxf(a + 0.1f * acc[m][n][j] - 0.1f * (a - tp), 0.f));
        }
  } else if (d.mode == M_PRED) {
#pragma unroll
    for (int m = 0; m < 8; ++m)
#pragma unroll
      for (int n = 0; n < 4; ++n)
#pragma unroll
        for (int j = 0; j < 4; ++j) {
          const size_t idx = IDX;
          float t = fast_tanh(acc[m][n][j]);
          d.o0[idx] = f2bf(t);
          float an = bf2f(d.i0[idx]);
          d.o1[idx] = f2bf((an - t) * (1.f - t * t));
        }
  } else {  // M_PART: f32 partial sums, one plane per split
    float* po = d.fout + (size_t)sk * 2048 * N;
#pragma unroll
    for (int m = 0; m < 8; ++m)
#pragma unroll
      for (int n = 0; n < 4; ++n)
#pragma unroll
        for (int j = 0; j < 4; ++j) {
          const size_t idx = IDX;
          po[idx] = acc[m][n][j];
        }
  }
#undef IDX
}

// ---------------- split-K combine: sum partials -> sigmoid -> d3, out ----------
__global__ void k_comb(const float* __restrict__ psum, const float* __restrict__ targ,
                       unsigned short* __restrict__ d3, float* __restrict__ out,
                       int n4, int ks) {
  const size_t plane4 = (size_t)2048 * 1024 / 4;
  int i = blockIdx.x * blockDim.x + threadIdx.x, st = gridDim.x * blockDim.x;
  for (; i < n4; i += st) {
    float4 s0 = ((const float4*)psum)[i];
    for (int s = 1; s < ks; ++s) {
      float4 sv = ((const float4*)psum)[i + s * plane4];
      s0.x += sv.x; s0.y += sv.y; s0.z += sv.z; s0.w += sv.w;
    }
    float4 tv = ((const float4*)targ)[i];
    float4 o; ushort4 dv; float sg;
    sg = fast_sig(s0.x); o.x = sg; dv.x = f2bf((tv.x - sg) * sg * (1.f - sg));
    sg = fast_sig(s0.y); o.y = sg; dv.y = f2bf((tv.y - sg) * sg * (1.f - sg));
    sg = fast_sig(s0.z); o.z = sg; dv.z = f2bf((tv.z - sg) * sg * (1.f - sg));
    sg = fast_sig(s0.w); o.w = sg; dv.w = f2bf((tv.w - sg) * sg * (1.f - sg));
    ((float4*)out)[i] = o;
    ((ushort4*)d3)[i] = dv;
  }
}

// ---------------- batched f32 -> bf16 conversion (8 jobs, one launch) ----------
struct CvtJobs {
  const float* src[8];
  unsigned short* dst[8];
  int n4[8];
};
__global__ void k_cvt8(CvtJobs J) {
  const int jb = blockIdx.y;
  const float* s = J.src[jb];
  unsigned short* dd = J.dst[jb];
  const int n4 = J.n4[jb];
  int i = blockIdx.x * blockDim.x + threadIdx.x, st = gridDim.x * blockDim.x;
  for (; i < n4; i += st) {
    float4 v = ((const float4*)s)[i];
    ushort4 o; o.x = f2bf(v.x); o.y = f2bf(v.y); o.z = f2bf(v.z); o.w = f2bf(v.w);
    ((ushort4*)dd)[i] = o;
  }
}

// ------------------------------------------------------------------------------------
extern "C" void kernel_launch(void* const* d_in, const int* in_sizes, int n_in,
                              void* d_out, int out_size, void* d_ws, size_t ws_size,
                              hipStream_t stream) {
  (void)in_sizes; (void)n_in; (void)out_size;
  const float* x      = (const float*)d_in[0];
  const float* target = (const float*)d_in[1];
  const float* wSrc[7] = {(const float*)d_in[2], (const float*)d_in[3],
                          (const float*)d_in[4], (const float*)d_in[5],
                          (const float*)d_in[6], (const float*)d_in[7],
                          (const float*)d_in[8]};
  const size_t wN[7] = {(size_t)4096 * 1024, (size_t)4096 * 4096, (size_t)4096 * 4096,
                        (size_t)1024 * 4096, (size_t)4096 * 4096, (size_t)4096 * 4096,
                        (size_t)4096 * 1024};

  char* w = (char*)d_ws;
  size_t off = 0;
  auto alloc = [&](size_t bytes) { void* p = w + off; off += bytes; return p; };

  const size_t BIG = (size_t)B_ * 4096;
  const size_t SML = (size_t)B_ * 1024;
  unsigned short* xb  = (unsigned short*)alloc(SML * 2);
  unsigned short* a1b = (unsigned short*)alloc(BIG * 2);
  unsigned short* a2b = (unsigned short*)alloc(BIG * 2);
  unsigned short* a3b = (unsigned short*)alloc(BIG * 2);
  unsigned short* t0b = (unsigned short*)alloc(BIG * 2);
  unsigned short* t1b = (unsigned short*)alloc(BIG * 2);
  unsigned short* t2b = (unsigned short*)alloc(BIG * 2);
  unsigned short* d1b = (unsigned short*)alloc(BIG * 2);
  unsigned short* d2b = (unsigned short*)alloc(BIG * 2);
  unsigned short* d3b = (unsigned short*)alloc(SML * 2);
  unsigned short* Wb[7];
  for (int i = 0; i < 7; ++i) Wb[i] = (unsigned short*)alloc(wN[i] * 2);

  // split-K partials for the N=1024 legs (p2/g3): adaptive to ws_size
  const size_t PS = SML * 4;  // 8 MB per split plane (f32 2048x1024)
  int KS = 1;
  if (ws_size >= off + 4 * PS) KS = 4;
  else if (ws_size >= off + 2 * PS) KS = 2;
  float* psum = (KS > 1) ? (float*)alloc((size_t)KS * PS) : nullptr;

  // ---- conversions: one batched launch ----
  CvtJobs J;
  for (int i = 0; i < 7; ++i) { J.src[i] = wSrc[i]; J.dst[i] = Wb[i]; J.n4[i] = (int)(wN[i] >> 2); }
  J.src[7] = x; J.dst[7] = xb; J.n4[7] = (int)(SML >> 2);
  k_cvt8<<<dim3(2048, 8), 256, 0, stream>>>(J);

  float* out = (float*)d_out;
  const int n4_sml = (int)(SML >> 2);
  auto desc = [&](const unsigned short* A, const unsigned short* W_, int K, int knt,
                  int N, int mode, unsigned short* o0, unsigned short* o1,
                  unsigned short* o2, const unsigned short* i0, const float* targ,
                  float* fout) {
    GDesc g; g.A = A; g.W = W_; g.o0 = o0; g.o1 = o1; g.o2 = o2; g.i0 = i0;
    g.targ = targ; g.fout = fout; g.K = K; g.knt = knt; g.N = N; g.mode = mode;
    return g;
  };
  // p2/g3 leg: split-K partials + combine, or direct M_SIG when KS==1
  auto launch_sig_leg = [&](const unsigned short* A) {
    if (KS > 1) {
      GDesc g = desc(A, Wb[3], 4096, 64 / KS, 1024, M_PART,
                     nullptr, nullptr, nullptr, nullptr, nullptr, psum);
      gemm8p<<<dim3(4, 8 * KS, 1), 512, LDS_BYTES, stream>>>(g, g, g);
      k_comb<<<2048, 256, 0, stream>>>(psum, target, d3b, out, n4_sml, KS);
    } else {
      GDesc g = desc(A, Wb[3], 4096, 64, 1024, M_SIG,
                     d3b, nullptr, nullptr, nullptr, target, out);
      gemm8p<<<dim3(4, 8, 1), 512, LDS_BYTES, stream>>>(g, g, g);
    }
  };

  // ---- initial feedforward (d1,d2 fused into g1/g2 epilogues) ----
  {
    GDesc g0 = desc(xb,  Wb[0], 1024, 16, 4096, M_ACT,  t0b, a1b, nullptr, nullptr, nullptr, nullptr);
    gemm8p<<<dim3(16, 8, 1), 512, LDS_BYTES, stream>>>(g0, g0, g0);
    GDesc g1 = desc(a1b, Wb[1], 4096, 64, 4096, M_ACTD, t1b, a2b, d1b, nullptr, nullptr, nullptr);
    gemm8p<<<dim3(16, 8, 1), 512, LDS_BYTES, stream>>>(g1, g1, g1);
    GDesc g2 = desc(a2b, Wb[2], 4096, 64, 4096, M_ACTD, t2b, a3b, d2b, nullptr, nullptr, nullptr);
    gemm8p<<<dim3(16, 8, 1), 512, LDS_BYTES, stream>>>(g2, g2, g2);
    launch_sig_leg(a3b);
  }

  // ---- 5 inference iterations ----
  for (int it = 0; it < 5; ++it) {
    // L_E: e0,e1 long (K=4096) + e2 short (K=1024) -- 384 blocks
    GDesc e0 = desc(d1b, Wb[4], 4096, 64, 4096, M_ERR, a1b, nullptr, nullptr, t0b, nullptr, nullptr);
    GDesc e1 = desc(d2b, Wb[5], 4096, 64, 4096, M_ERR, a2b, nullptr, nullptr, t1b, nullptr, nullptr);
    GDesc e2 = desc(d3b, Wb[6], 1024, 16, 4096, M_ERR, a3b, nullptr, nullptr, t2b, nullptr, nullptr);
    gemm8p<<<dim3(16, 8, 3), 512, LDS_BYTES, stream>>>(e0, e1, e2);
    // L_P: p0,p1 -- exactly 256 blocks
    GDesc p0 = desc(a1b, Wb[1], 4096, 64, 4096, M_PRED, t1b, d1b, nullptr, a2b, nullptr, nullptr);
    GDesc p1 = desc(a2b, Wb[2], 4096, 64, 4096, M_PRED, t2b, d2b, nullptr, a3b, nullptr, nullptr);
    gemm8p<<<dim3(16, 8, 2), 512, LDS_BYTES, stream>>>(p0, p1, p1);
    // L_P2: p2 split-K (+combine)
    launch_sig_leg(a3b);
  }
}

// Round 9
// 2255.201 us; speedup vs baseline: 1.1875x; 1.0463x over previous
//
#include <hip/hip_runtime.h>
#include <stdint.h>

// Predictive-coding inference: LAYER_SZS=[1024,4096,4096,4096,1024], B=2048, 5 iters.
// GEMM: C[M,N] = A[M,K](bf16) @ W[N,K](bf16)^T, f32 accum, fused epilogues.
// m97/m103 structure (874-912 TF proven): 128x128 tile, BK=64, 4 waves (2x2),
// single-buffered 32KB static LDS, per tile {stage 8x gload_lds; vmcnt(0)+barrier;
// read+MFMA; barrier}. Overlap comes from 3+ independent blocks/CU (m114), not
// intra-block scheduling (5 lockstep schedules all capped at ~620 TF, R4-R8).
// + XOR bank-swizzle (conflicts=0, R4) -- the combo never tested in R2/R3.
// Batched legs (z=3) for 4-6 blocks/CU; split-K for N=1024 legs; fused epilogues.

typedef __attribute__((ext_vector_type(8))) __bf16 bf16x8;
typedef __attribute__((ext_vector_type(4))) float f32x4;

#define B_ 2048

__device__ __forceinline__ unsigned short f2bf(float f) {
  union { float f; unsigned u; } v; v.f = f;
  unsigned u = v.u;
  u += 0x7FFFu + ((u >> 16) & 1u);
  return (unsigned short)(u >> 16);
}
__device__ __forceinline__ float bf2f(unsigned short s) {
  union { unsigned u; float f; } v; v.u = ((unsigned)s) << 16;
  return v.f;
}
__device__ __forceinline__ float fast_sig(float x) { return 1.0f / (1.0f + __expf(-x)); }
__device__ __forceinline__ float fast_tanh(float x) {
  return 1.0f - 2.0f / (__expf(2.0f * x) + 1.0f);
}
__device__ __forceinline__ void gload_lds16(const void* g, void* l) {
  __builtin_amdgcn_global_load_lds((const __attribute__((address_space(1))) void*)g,
                                   (__attribute__((address_space(3))) void*)l, 16, 0, 0);
}

// epilogue modes
#define M_ACT  0   // o0=t=tanh(acc); o1=relu(t)
#define M_ACTD 1   // + o2 = d = (relu(t)-t)(1-t^2)
#define M_SIG  2   // s=sig(acc); o0=(targ-s)s(1-s); fout=s
#define M_ERR  3   // o0(a) = relu(a + 0.1*acc - 0.1*(a - i0))
#define M_PRED 4   // t=tanh(acc); o0=t; o1=(i0 - t)(1-t^2)
#define M_PART 5   // fout[sk-plane] = acc (f32 partial sums, split-K)

struct GDesc {
  const unsigned short* A;   // [M,K]
  const unsigned short* W;   // [N,K]
  unsigned short* o0;
  unsigned short* o1;
  unsigned short* o2;
  const unsigned short* i0;
  const float* targ;
  float* fout;
  int K;     // row stride (elements)
  int knt;   // K-tiles (BK=64) per block
  int N, mode;
};

__global__ __launch_bounds__(256, 3) void gemm128(GDesc d0, GDesc d1, GDesc d2) {
  const GDesc d = (blockIdx.z == 0) ? d0 : (blockIdx.z == 1 ? d1 : d2);

  __shared__ alignas(16) unsigned short As[128 * 64];
  __shared__ alignas(16) unsigned short Bs[128 * 64];

  const int tid = threadIdx.x;
  const int wid = tid >> 6, lane = tid & 63;
  const int wr = wid >> 1, wc = wid & 1;      // 2 x 2 waves
  const int q = lane >> 4, j16 = lane & 15, r3 = j16 & 7;
  const int K = d.K, N = d.N, nt = d.knt;

  const int sk  = blockIdx.y >> 4;            // split-K plane (0 unless split leg)
  const int row0 = (blockIdx.y & 15) << 7;    // BM = 128
  const int col0 = blockIdx.x << 7;           // BN = 128
  const int kbeg = (sk * nt) << 6;

  // staging constants: thread covers rows rbase+32*i, 16B chunk (tid&7);
  // global source chunk XOR-swizzled by row&7; LDS dest linear (HW adds lane*16B)
  const int rbase = (wid << 3) + (lane >> 3);                 // 0..31
  const int csw   = ((lane & 7) ^ ((lane >> 3) & 7)) << 3;    // swizzled chunk (shorts)
  const unsigned short* Ag = d.A + (size_t)row0 * K;
  const unsigned short* Bg = d.W + (size_t)col0 * K;
  const int ldst = wid << 9;                                  // wid*512 shorts

  // LDS read offsets (shorts), loop-invariant; swizzle matches staging
  int aoff[4][2], boff[4][2];
#pragma unroll
  for (int m = 0; m < 4; ++m)
#pragma unroll
    for (int ks = 0; ks < 2; ++ks) {
      aoff[m][ks] = (wr * 64 + m * 16 + j16) * 64 + (((ks * 4 + q) ^ r3) << 3);
      boff[m][ks] = (wc * 64 + m * 16 + j16) * 64 + (((ks * 4 + q) ^ r3) << 3);
    }

  f32x4 acc[4][4];
#pragma unroll
  for (int m = 0; m < 4; ++m)
#pragma unroll
    for (int n = 0; n < 4; ++n) acc[m][n] = (f32x4){0.f, 0.f, 0.f, 0.f};

  for (int t = 0; t < nt; ++t) {
    const int k0 = kbeg + (t << 6);
    // stage tile t (single buffer): 4 A + 4 B gload_lds per thread
#pragma unroll
    for (int i = 0; i < 4; ++i)
      gload_lds16(Ag + (size_t)((i << 5) + rbase) * K + k0 + csw,
                  As + (i << 11) + ldst);
#pragma unroll
    for (int i = 0; i < 4; ++i)
      gload_lds16(Bg + (size_t)((i << 5) + rbase) * K + k0 + csw,
                  Bs + (i << 11) + ldst);
    asm volatile("s_waitcnt vmcnt(0)" ::: "memory");
    __builtin_amdgcn_s_barrier();

#pragma unroll
    for (int ks = 0; ks < 2; ++ks) {
      bf16x8 av[4], bv[4];
#pragma unroll
      for (int m = 0; m < 4; ++m) av[m] = *(const bf16x8*)(As + aoff[m][ks]);
#pragma unroll
      for (int n = 0; n < 4; ++n) bv[n] = *(const bf16x8*)(Bs + boff[n][ks]);
#pragma unroll
      for (int m = 0; m < 4; ++m)
#pragma unroll
        for (int n = 0; n < 4; ++n)
          acc[m][n] = __builtin_amdgcn_mfma_f32_16x16x32_bf16(av[m], bv[n], acc[m][n], 0, 0, 0);
    }
    __builtin_amdgcn_s_barrier();
  }

  // epilogue: D row=(lane>>4)*4+j, col=lane&15 (m89-verified layout)
#define IDX (size_t)(row0 + wr * 64 + m * 16 + (q << 2) + j) * N \
          + (col0 + wc * 64 + n * 16 + j16)
  if (d.mode == M_ACT) {
#pragma unroll
    for (int m = 0; m < 4; ++m)
#pragma unroll
      for (int n = 0; n < 4; ++n)
#pragma unroll
        for (int j = 0; j < 4; ++j) {
          const size_t idx = IDX;
          float t = fast_tanh(acc[m][n][j]);
          d.o0[idx] = f2bf(t);
          d.o1[idx] = f2bf(fmaxf(t, 0.f));
        }
  } else if (d.mode == M_ACTD) {
#pragma unroll
    for (int m = 0; m < 4; ++m)
#pragma unroll
      for (int n = 0; n < 4; ++n)
#pragma unroll
        for (int j = 0; j < 4; ++j) {
          const size_t idx = IDX;
          float t = fast_tanh(acc[m][n][j]);
          d.o0[idx] = f2bf(t);
          d.o1[idx] = f2bf(fmaxf(t, 0.f));
          d.o2[idx] = f2bf(t >= 0.f ? 0.f : (-t) * (1.f - t * t));
        }
  } else if (d.mode == M_SIG) {
#pragma unroll
    for (int m = 0; m < 4; ++m)
#pragma unroll
      for (int n = 0; n < 4; ++n)
#pragma unroll
        for (int j = 0; j < 4; ++j) {
          const size_t idx = IDX;
          float s = fast_sig(acc[m][n][j]);
          d.fout[idx] = s;
          d.o0[idx] = f2bf((d.targ[idx] - s) * s * (1.f - s));
        }
  } else if (d.mode == M_ERR) {
#pragma unroll
    for (int m = 0; m < 4; ++m)
#pragma unroll
      for (int n = 0; n < 4; ++n)
#pragma unroll
        for (int j = 0; j < 4; ++j) {
          const size_t idx = IDX;
          float a = bf2f(d.o0[idx]);
          float tp = bf2f(d.i0[idx]);
          d.o0[idx] = f2bf(fmaxf(a + 0.1f * acc[m][n][j] - 0.1f * (a - tp), 0.f));
        }
  } else if (d.mode == M_PRED) {
#pragma unroll
    for (int m = 0; m < 4; ++m)
#pragma unroll
      for (int n = 0; n < 4; ++n)
#pragma unroll
        for (int j = 0; j < 4; ++j) {
          const size_t idx = IDX;
          float t = fast_tanh(acc[m][n][j]);
          d.o0[idx] = f2bf(t);
          float an = bf2f(d.i0[idx]);
          d.o1[idx] = f2bf((an - t) * (1.f - t * t));
        }
  } else {  // M_PART: f32 partial sums, one plane per split
    float* po = d.fout + (size_t)sk * 2048 * N;
#pragma unroll
    for (int m = 0; m < 4; ++m)
#pragma unroll
      for (int n = 0; n < 4; ++n)
#pragma unroll
        for (int j = 0; j < 4; ++j) {
          const size_t idx = IDX;
          po[idx] = acc[m][n][j];
        }
  }
#undef IDX
}

// ---------------- split-K combine: sum partials -> sigmoid -> d3, out ----------
__global__ void k_comb(const float* __restrict__ psum, const float* __restrict__ targ,
                       unsigned short* __restrict__ d3, float* __restrict__ out,
                       int n4, int ks) {
  const size_t plane4 = (size_t)2048 * 1024 / 4;
  int i = blockIdx.x * blockDim.x + threadIdx.x, st = gridDim.x * blockDim.x;
  for (; i < n4; i += st) {
    float4 s0 = ((const float4*)psum)[i];
    for (int s = 1; s < ks; ++s) {
      float4 sv = ((const float4*)psum)[i + s * plane4];
      s0.x += sv.x; s0.y += sv.y; s0.z += sv.z; s0.w += sv.w;
    }
    float4 tv = ((const float4*)targ)[i];
    float4 o; ushort4 dv; float sg;
    sg = fast_sig(s0.x); o.x = sg; dv.x = f2bf((tv.x - sg) * sg * (1.f - sg));
    sg = fast_sig(s0.y); o.y = sg; dv.y = f2bf((tv.y - sg) * sg * (1.f - sg));
    sg = fast_sig(s0.z); o.z = sg; dv.z = f2bf((tv.z - sg) * sg * (1.f - sg));
    sg = fast_sig(s0.w); o.w = sg; dv.w = f2bf((tv.w - sg) * sg * (1.f - sg));
    ((float4*)out)[i] = o;
    ((ushort4*)d3)[i] = dv;
  }
}

// ---------------- batched f32 -> bf16 conversion (8 jobs, one launch) ----------
struct CvtJobs {
  const float* src[8];
  unsigned short* dst[8];
  int n4[8];
};
__global__ void k_cvt8(CvtJobs J) {
  const int jb = blockIdx.y;
  const float* s = J.src[jb];
  unsigned short* dd = J.dst[jb];
  const int n4 = J.n4[jb];
  int i = blockIdx.x * blockDim.x + threadIdx.x, st = gridDim.x * blockDim.x;
  for (; i < n4; i += st) {
    float4 v = ((const float4*)s)[i];
    ushort4 o; o.x = f2bf(v.x); o.y = f2bf(v.y); o.z = f2bf(v.z); o.w = f2bf(v.w);
    ((ushort4*)dd)[i] = o;
  }
}

// ------------------------------------------------------------------------------------
extern "C" void kernel_launch(void* const* d_in, const int* in_sizes, int n_in,
                              void* d_out, int out_size, void* d_ws, size_t ws_size,
                              hipStream_t stream) {
  (void)in_sizes; (void)n_in; (void)out_size;
  const float* x      = (const float*)d_in[0];
  const float* target = (const float*)d_in[1];
  const float* wSrc[7] = {(const float*)d_in[2], (const float*)d_in[3],
                          (const float*)d_in[4], (const float*)d_in[5],
                          (const float*)d_in[6], (const float*)d_in[7],
                          (const float*)d_in[8]};
  const size_t wN[7] = {(size_t)4096 * 1024, (size_t)4096 * 4096, (size_t)4096 * 4096,
                        (size_t)1024 * 4096, (size_t)4096 * 4096, (size_t)4096 * 4096,
                        (size_t)4096 * 1024};

  char* w = (char*)d_ws;
  size_t off = 0;
  auto alloc = [&](size_t bytes) { void* p = w + off; off += bytes; return p; };

  const size_t BIG = (size_t)B_ * 4096;
  const size_t SML = (size_t)B_ * 1024;
  unsigned short* xb  = (unsigned short*)alloc(SML * 2);
  unsigned short* a1b = (unsigned short*)alloc(BIG * 2);
  unsigned short* a2b = (unsigned short*)alloc(BIG * 2);
  unsigned short* a3b = (unsigned short*)alloc(BIG * 2);
  unsigned short* t0b = (unsigned short*)alloc(BIG * 2);
  unsigned short* t1b = (unsigned short*)alloc(BIG * 2);
  unsigned short* t2b = (unsigned short*)alloc(BIG * 2);
  unsigned short* d1b = (unsigned short*)alloc(BIG * 2);
  unsigned short* d2b = (unsigned short*)alloc(BIG * 2);
  unsigned short* d3b = (unsigned short*)alloc(SML * 2);
  unsigned short* Wb[7];
  for (int i = 0; i < 7; ++i) Wb[i] = (unsigned short*)alloc(wN[i] * 2);

  // split-K partials for the N=1024 legs (p2/g3): adaptive to ws_size
  const size_t PS = SML * 4;  // 8 MB per split plane (f32 2048x1024)
  int KS = 1;
  if (ws_size >= off + 4 * PS) KS = 4;
  else if (ws_size >= off + 2 * PS) KS = 2;
  float* psum = (KS > 1) ? (float*)alloc((size_t)KS * PS) : nullptr;

  // ---- conversions: one batched launch ----
  CvtJobs J;
  for (int i = 0; i < 7; ++i) { J.src[i] = wSrc[i]; J.dst[i] = Wb[i]; J.n4[i] = (int)(wN[i] >> 2); }
  J.src[7] = x; J.dst[7] = xb; J.n4[7] = (int)(SML >> 2);
  k_cvt8<<<dim3(2048, 8), 256, 0, stream>>>(J);

  float* out = (float*)d_out;
  const int n4_sml = (int)(SML >> 2);
  auto desc = [&](const unsigned short* A, const unsigned short* W_, int K, int knt,
                  int N, int mode, unsigned short* o0, unsigned short* o1,
                  unsigned short* o2, const unsigned short* i0, const float* targ,
                  float* fout) {
    GDesc g; g.A = A; g.W = W_; g.o0 = o0; g.o1 = o1; g.o2 = o2; g.i0 = i0;
    g.targ = targ; g.fout = fout; g.K = K; g.knt = knt; g.N = N; g.mode = mode;
    return g;
  };
  // p2/g3 leg: split-K partials + combine, or direct M_SIG when KS==1
  auto launch_sig_leg = [&](const unsigned short* A) {
    if (KS > 1) {
      GDesc g = desc(A, Wb[3], 4096, 64 / KS, 1024, M_PART,
                     nullptr, nullptr, nullptr, nullptr, nullptr, psum);
      gemm128<<<dim3(8, 16 * KS, 1), 256, 0, stream>>>(g, g, g);
      k_comb<<<2048, 256, 0, stream>>>(psum, target, d3b, out, n4_sml, KS);
    } else {
      GDesc g = desc(A, Wb[3], 4096, 64, 1024, M_SIG,
                     d3b, nullptr, nullptr, nullptr, target, out);
      gemm128<<<dim3(8, 16, 1), 256, 0, stream>>>(g, g, g);
    }
  };

  // ---- initial feedforward (d1,d2 fused into g1/g2 epilogues) ----
  {
    GDesc g0 = desc(xb,  Wb[0], 1024, 16, 4096, M_ACT,  t0b, a1b, nullptr, nullptr, nullptr, nullptr);
    gemm128<<<dim3(32, 16, 1), 256, 0, stream>>>(g0, g0, g0);
    GDesc g1 = desc(a1b, Wb[1], 4096, 64, 4096, M_ACTD, t1b, a2b, d1b, nullptr, nullptr, nullptr);
    gemm128<<<dim3(32, 16, 1), 256, 0, stream>>>(g1, g1, g1);
    GDesc g2 = desc(a2b, Wb[2], 4096, 64, 4096, M_ACTD, t2b, a3b, d2b, nullptr, nullptr, nullptr);
    gemm128<<<dim3(32, 16, 1), 256, 0, stream>>>(g2, g2, g2);
    launch_sig_leg(a3b);
  }

  // ---- 5 inference iterations ----
  for (int it = 0; it < 5; ++it) {
    // L_E: e0,e1 long (K=4096) + e2 short (K=1024) -- 1536 blocks (6/CU)
    GDesc e0 = desc(d1b, Wb[4], 4096, 64, 4096, M_ERR, a1b, nullptr, nullptr, t0b, nullptr, nullptr);
    GDesc e1 = desc(d2b, Wb[5], 4096, 64, 4096, M_ERR, a2b, nullptr, nullptr, t1b, nullptr, nullptr);
    GDesc e2 = desc(d3b, Wb[6], 1024, 16, 4096, M_ERR, a3b, nullptr, nullptr, t2b, nullptr, nullptr);
    gemm128<<<dim3(32, 16, 3), 256, 0, stream>>>(e0, e1, e2);
    // L_P: p0,p1 -- 1024 blocks (4/CU)
    GDesc p0 = desc(a1b, Wb[1], 4096, 64, 4096, M_PRED, t1b, d1b, nullptr, a2b, nullptr, nullptr);
    GDesc p1 = desc(a2b, Wb[2], 4096, 64, 4096, M_PRED, t2b, d2b, nullptr, a3b, nullptr, nullptr);
    gemm128<<<dim3(32, 16, 2), 256, 0, stream>>>(p0, p1, p1);
    // L_P2: p2 split-K (+combine)
    launch_sig_leg(a3b);
  }
}

// Round 10
// 2245.706 us; speedup vs baseline: 1.1925x; 1.0042x over previous
//
#include <hip/hip_runtime.h>
#include <stdint.h>

// Predictive-coding inference: LAYER_SZS=[1024,4096,4096,4096,1024], B=2048, 5 iters.
// Two GEMM kernels, each used where its grid shape is balanced:
//  - gemm8p: 256x256 8-phase (R8), LDS 128KB, 1 blk/CU -- ONLY for exact-256-block
//    balanced pairs {e0,e1}, {p0,p1} (deduced ~950 TF when balanced; R8's slowdown
//    was grid imbalance: 384-block batches + 128-block FF at half-CU occupancy).
//  - gemm128: 128x128 m97-style (R9, 797 TF measured), LDS 32KB, 2-6 blk/CU --
//    for e2/FF/sig-leg where grids aren't multiples of 256.
// All C[M,N] = A[M,K](bf16) @ W[N,K](bf16)^T, f32 accum, fused epilogues,
// XOR bank-swizzle both-sides (conflicts = 0 since R4).

typedef __attribute__((ext_vector_type(8))) __bf16 bf16x8;
typedef __attribute__((ext_vector_type(4))) float f32x4;

#define B_ 2048
#define HALF_SH 8192                 // shorts per half-tile (128 rows x 64 cols)
#define LDS_BYTES (8 * HALF_SH * 2)  // 131072

__device__ __forceinline__ unsigned short f2bf(float f) {
  union { float f; unsigned u; } v; v.f = f;
  unsigned u = v.u;
  u += 0x7FFFu + ((u >> 16) & 1u);
  return (unsigned short)(u >> 16);
}
__device__ __forceinline__ float bf2f(unsigned short s) {
  union { unsigned u; float f; } v; v.u = ((unsigned)s) << 16;
  return v.f;
}
__device__ __forceinline__ float fast_sig(float x) { return 1.0f / (1.0f + __expf(-x)); }
__device__ __forceinline__ float fast_tanh(float x) {
  return 1.0f - 2.0f / (__expf(2.0f * x) + 1.0f);
}
__device__ __forceinline__ void gload_lds16(const void* g, void* l) {
  __builtin_amdgcn_global_load_lds((const __attribute__((address_space(1))) void*)g,
                                   (__attribute__((address_space(3))) void*)l, 16, 0, 0);
}

// epilogue modes
#define M_ACT  0   // o0=t=tanh(acc); o1=relu(t)
#define M_ACTD 1   // + o2 = d = (relu(t)-t)(1-t^2)
#define M_SIG  2   // s=sig(acc); o0=(targ-s)s(1-s); fout=s
#define M_ERR  3   // o0(a) = relu(a + 0.1*acc - 0.1*(a - i0))
#define M_PRED 4   // t=tanh(acc); o0=t; o1=(i0 - t)(1-t^2)
#define M_PART 5   // fout[sk-plane] = acc (f32 partial sums, split-K)

struct GDesc {
  const unsigned short* A;   // [M,K]
  const unsigned short* W;   // [N,K]
  unsigned short* o0;
  unsigned short* o1;
  unsigned short* o2;
  const unsigned short* i0;
  const float* targ;
  float* fout;
  int K;     // row stride (elements)
  int knt;   // K-tiles (BK=64) per block
  int N, mode;
};

// ===================== gemm8p: 256x256, 8 waves, 8-phase (R8) =====================
__global__ __launch_bounds__(512, 2) void gemm8p(GDesc d0, GDesc d1, GDesc d2) {
  const GDesc d = (blockIdx.z == 0) ? d0 : (blockIdx.z == 1 ? d1 : d2);

  extern __shared__ __attribute__((aligned(16))) unsigned short lds[];
  unsigned short* Alds = lds;                 // [buf][h] x HALF_SH
  unsigned short* Blds = lds + 4 * HALF_SH;   // [buf][v] x HALF_SH

  const int tid = threadIdx.x;
  const int wid = tid >> 6, lane = tid & 63;
  const int wr = wid >> 2, wc = wid & 3;      // 2 x 4 waves
  const int q = lane >> 4, j16 = lane & 15, r3 = j16 & 7;
  const int K = d.K, N = d.N, nt = d.knt;

  const int sk  = blockIdx.y >> 3;
  const int row0 = (blockIdx.y & 7) << 8;     // BM = 256
  const int col0 = blockIdx.x << 8;           // BN = 256
  const int kbeg = (sk * nt) << 6;

  const int rbase = (wid << 3) + (lane >> 3);
  const int csw   = ((lane & 7) ^ ((lane >> 3) & 7)) << 3;
  const unsigned short* Ag = d.A + (size_t)row0 * K;
  const unsigned short* Bg = d.W + (size_t)col0 * K;
  const int ldst = wid << 9;

#define STAGE_AP(buf_, h_, k0_) do { \
  unsigned short* slot_ = Alds + (((buf_) << 1) + (h_)) * HALF_SH; \
  _Pragma("unroll") \
  for (int i_ = 0; i_ < 2; ++i_) \
    gload_lds16(Ag + (size_t)(((h_) << 7) + (i_ << 6) + rbase) * K + (k0_) + csw, \
                slot_ + (i_ << 12) + ldst); \
} while (0)
#define STAGE_BP(buf_, v_, k0_) do { \
  unsigned short* slot_ = Blds + (((buf_) << 1) + (v_)) * HALF_SH; \
  _Pragma("unroll") \
  for (int i_ = 0; i_ < 2; ++i_) \
    gload_lds16(Bg + (size_t)(((v_) << 7) + (i_ << 6) + rbase) * K + (k0_) + csw, \
                slot_ + (i_ << 12) + ldst); \
} while (0)

  int aoff[4][2], boff[2][2];
#pragma unroll
  for (int m = 0; m < 4; ++m)
#pragma unroll
    for (int ks = 0; ks < 2; ++ks)
      aoff[m][ks] = (wr * 64 + m * 16 + j16) * 64 + (((ks * 4 + q) ^ r3) << 3);
#pragma unroll
  for (int n = 0; n < 2; ++n)
#pragma unroll
    for (int ks = 0; ks < 2; ++ks)
      boff[n][ks] = (wc * 32 + n * 16 + j16) * 64 + (((ks * 4 + q) ^ r3) << 3);

  f32x4 acc[8][4];
#pragma unroll
  for (int m = 0; m < 8; ++m)
#pragma unroll
    for (int n = 0; n < 4; ++n) acc[m][n] = (f32x4){0.f, 0.f, 0.f, 0.f};

  bf16x8 av0[2][4], av1[2][4], bv0[2][2], bv1[2][2];

#define LDAP(dst_, slot_) do { \
  _Pragma("unroll") \
  for (int ks_ = 0; ks_ < 2; ++ks_) \
    _Pragma("unroll") \
    for (int m_ = 0; m_ < 4; ++m_) \
      dst_[ks_][m_] = *(const bf16x8*)((slot_) + aoff[m_][ks_]); \
} while (0)
#define LDBP(dst_, slot_) do { \
  _Pragma("unroll") \
  for (int ks_ = 0; ks_ < 2; ++ks_) \
    _Pragma("unroll") \
    for (int n_ = 0; n_ < 2; ++n_) \
      dst_[ks_][n_] = *(const bf16x8*)((slot_) + boff[n_][ks_]); \
} while (0)
#define MMP(avv_, bvv_, mb_, nb_) do { \
  __builtin_amdgcn_s_setprio(1); \
  _Pragma("unroll") \
  for (int ks_ = 0; ks_ < 2; ++ks_) \
    _Pragma("unroll") \
    for (int m_ = 0; m_ < 4; ++m_) \
      _Pragma("unroll") \
      for (int n_ = 0; n_ < 2; ++n_) \
        acc[(mb_) + m_][(nb_) + n_] = __builtin_amdgcn_mfma_f32_16x16x32_bf16( \
            avv_[ks_][m_], bvv_[ks_][n_], acc[(mb_) + m_][(nb_) + n_], 0, 0, 0); \
  __builtin_amdgcn_s_setprio(0); \
} while (0)
#define BARP __builtin_amdgcn_s_barrier()
#define LGKM0P asm volatile("s_waitcnt lgkmcnt(0)" ::: "memory")

  // prologue: t0 all 4 halves + t1 first 3; vmcnt(6) => t0 resident
  STAGE_AP(0, 0, kbeg);
  STAGE_BP(0, 0, kbeg);
  STAGE_BP(0, 1, kbeg);
  STAGE_AP(0, 1, kbeg);
  {
    const int k1 = kbeg + ((1 < nt ? 1 : 0) << 6);
    STAGE_AP(1, 0, k1);
    STAGE_BP(1, 0, k1);
    STAGE_BP(1, 1, k1);
  }
  asm volatile("s_waitcnt vmcnt(6)" ::: "memory");
  BARP;

  for (int t = 0; t < nt; ++t) {
    const int buf = t & 1;
    const int b1 = (t + 1) & 1, b2 = t & 1;
    const int k1 = kbeg + (((t + 1) < nt ? (t + 1) : 0) << 6);
    const int k2 = kbeg + (((t + 2) < nt ? (t + 2) : 0) << 6);
    const unsigned short* As0 = Alds + ((buf << 1) + 0) * HALF_SH;
    const unsigned short* As1 = Alds + ((buf << 1) + 1) * HALF_SH;
    const unsigned short* Bs0 = Blds + ((buf << 1) + 0) * HALF_SH;
    const unsigned short* Bs1 = Blds + ((buf << 1) + 1) * HALF_SH;

    // P1: reads av0,bv0 (12); stages (t+1):A1
    LDAP(av0, As0);
    LDBP(bv0, Bs0);
    STAGE_AP(b1, 1, k1);
    asm volatile("s_waitcnt lgkmcnt(8)" ::: "memory");
    BARP;
    LGKM0P;
    MMP(av0, bv0, 0, 0);
    BARP;
    // P2: reads bv1 (4); stages (t+2):A0
    LDBP(bv1, Bs1);
    STAGE_AP(b2, 0, k2);
    BARP;
    LGKM0P;
    MMP(av0, bv1, 0, 2);
    BARP;
    // P3: reads av1 (8); stages (t+2):B0
    LDAP(av1, As1);
    STAGE_BP(b2, 0, k2);
    BARP;
    LGKM0P;
    MMP(av1, bv1, 4, 2);
    BARP;
    // P4: no reads; stages (t+2):B1; counted vmcnt(6) => tile t+1 resident
    STAGE_BP(b2, 1, k2);
    asm volatile("s_waitcnt vmcnt(6)" ::: "memory");
    BARP;
    MMP(av1, bv0, 4, 0);
    BARP;
  }
  asm volatile("s_waitcnt vmcnt(0)" ::: "memory");
  BARP;

#define IDX8 (size_t)(row0 + ((m >> 2) << 7) + wr * 64 + (m & 3) * 16 + (q << 2) + j) * N \
           + (col0 + ((n >> 1) << 7) + wc * 32 + (n & 1) * 16 + j16)
  if (d.mode == M_ERR) {
#pragma unroll
    for (int m = 0; m < 8; ++m)
#pragma unroll
      for (int n = 0; n < 4; ++n)
#pragma unroll
        for (int j = 0; j < 4; ++j) {
          const size_t idx = IDX8;
          float a = bf2f(d.o0[idx]);
          float tp = bf2f(d.i0[idx]);
          d.o0[idx] = f2bf(fmaxf(a + 0.1f * acc[m][n][j] - 0.1f * (a - tp), 0.f));
        }
  } else if (d.mode == M_PRED) {
#pragma unroll
    for (int m = 0; m < 8; ++m)
#pragma unroll
      for (int n = 0; n < 4; ++n)
#pragma unroll
        for (int j = 0; j < 4; ++j) {
          const size_t idx = IDX8;
          float t = fast_tanh(acc[m][n][j]);
          d.o0[idx] = f2bf(t);
          float an = bf2f(d.i0[idx]);
          d.o1[idx] = f2bf((an - t) * (1.f - t * t));
        }
  } else {  // M_ACT (unused here but kept valid)
#pragma unroll
    for (int m = 0; m < 8; ++m)
#pragma unroll
      for (int n = 0; n < 4; ++n)
#pragma unroll
        for (int j = 0; j < 4; ++j) {
          const size_t idx = IDX8;
          float t = fast_tanh(acc[m][n][j]);
          d.o0[idx] = f2bf(t);
          d.o1[idx] = f2bf(fmaxf(t, 0.f));
        }
  }
#undef IDX8
}

// ===================== gemm128: 128x128, 4 waves, m97-style (R9) ==================
__global__ __launch_bounds__(256, 4) void gemm128(GDesc d0, GDesc d1, GDesc d2) {
  const GDesc d = (blockIdx.z == 0) ? d0 : (blockIdx.z == 1 ? d1 : d2);

  __shared__ alignas(16) unsigned short As[128 * 64];
  __shared__ alignas(16) unsigned short Bs[128 * 64];

  const int tid = threadIdx.x;
  const int wid = tid >> 6, lane = tid & 63;
  const int wr = wid >> 1, wc = wid & 1;      // 2 x 2 waves
  const int q = lane >> 4, j16 = lane & 15, r3 = j16 & 7;
  const int K = d.K, N = d.N, nt = d.knt;

  const int sk  = blockIdx.y >> 4;
  const int row0 = (blockIdx.y & 15) << 7;    // BM = 128
  const int col0 = blockIdx.x << 7;           // BN = 128
  const int kbeg = (sk * nt) << 6;

  const int rbase = (wid << 3) + (lane >> 3);                 // 0..31
  const int csw   = ((lane & 7) ^ ((lane >> 3) & 7)) << 3;
  const unsigned short* Ag = d.A + (size_t)row0 * K;
  const unsigned short* Bg = d.W + (size_t)col0 * K;
  const int ldst = wid << 9;

  int aoff[4][2], boff[4][2];
#pragma unroll
  for (int m = 0; m < 4; ++m)
#pragma unroll
    for (int ks = 0; ks < 2; ++ks) {
      aoff[m][ks] = (wr * 64 + m * 16 + j16) * 64 + (((ks * 4 + q) ^ r3) << 3);
      boff[m][ks] = (wc * 64 + m * 16 + j16) * 64 + (((ks * 4 + q) ^ r3) << 3);
    }

  f32x4 acc[4][4];
#pragma unroll
  for (int m = 0; m < 4; ++m)
#pragma unroll
    for (int n = 0; n < 4; ++n) acc[m][n] = (f32x4){0.f, 0.f, 0.f, 0.f};

  for (int t = 0; t < nt; ++t) {
    const int k0 = kbeg + (t << 6);
#pragma unroll
    for (int i = 0; i < 4; ++i)
      gload_lds16(Ag + (size_t)((i << 5) + rbase) * K + k0 + csw,
                  As + (i << 11) + ldst);
#pragma unroll
    for (int i = 0; i < 4; ++i)
      gload_lds16(Bg + (size_t)((i << 5) + rbase) * K + k0 + csw,
                  Bs + (i << 11) + ldst);
    asm volatile("s_waitcnt vmcnt(0)" ::: "memory");
    __builtin_amdgcn_s_barrier();

#pragma unroll
    for (int ks = 0; ks < 2; ++ks) {
      bf16x8 av[4], bv[4];
#pragma unroll
      for (int m = 0; m < 4; ++m) av[m] = *(const bf16x8*)(As + aoff[m][ks]);
#pragma unroll
      for (int n = 0; n < 4; ++n) bv[n] = *(const bf16x8*)(Bs + boff[n][ks]);
#pragma unroll
      for (int m = 0; m < 4; ++m)
#pragma unroll
        for (int n = 0; n < 4; ++n)
          acc[m][n] = __builtin_amdgcn_mfma_f32_16x16x32_bf16(av[m], bv[n], acc[m][n], 0, 0, 0);
    }
    __builtin_amdgcn_s_barrier();
  }

#define IDX (size_t)(row0 + wr * 64 + m * 16 + (q << 2) + j) * N \
          + (col0 + wc * 64 + n * 16 + j16)
  if (d.mode == M_ACT) {
#pragma unroll
    for (int m = 0; m < 4; ++m)
#pragma unroll
      for (int n = 0; n < 4; ++n)
#pragma unroll
        for (int j = 0; j < 4; ++j) {
          const size_t idx = IDX;
          float t = fast_tanh(acc[m][n][j]);
          d.o0[idx] = f2bf(t);
          d.o1[idx] = f2bf(fmaxf(t, 0.f));
        }
  } else if (d.mode == M_ACTD) {
#pragma unroll
    for (int m = 0; m < 4; ++m)
#pragma unroll
      for (int n = 0; n < 4; ++n)
#pragma unroll
        for (int j = 0; j < 4; ++j) {
          const size_t idx = IDX;
          float t = fast_tanh(acc[m][n][j]);
          d.o0[idx] = f2bf(t);
          d.o1[idx] = f2bf(fmaxf(t, 0.f));
          d.o2[idx] = f2bf(t >= 0.f ? 0.f : (-t) * (1.f - t * t));
        }
  } else if (d.mode == M_SIG) {
#pragma unroll
    for (int m = 0; m < 4; ++m)
#pragma unroll
      for (int n = 0; n < 4; ++n)
#pragma unroll
        for (int j = 0; j < 4; ++j) {
          const size_t idx = IDX;
          float s = fast_sig(acc[m][n][j]);
          d.fout[idx] = s;
          d.o0[idx] = f2bf((d.targ[idx] - s) * s * (1.f - s));
        }
  } else if (d.mode == M_ERR) {
#pragma unroll
    for (int m = 0; m < 4; ++m)
#pragma unroll
      for (int n = 0; n < 4; ++n)
#pragma unroll
        for (int j = 0; j < 4; ++j) {
          const size_t idx = IDX;
          float a = bf2f(d.o0[idx]);
          float tp = bf2f(d.i0[idx]);
          d.o0[idx] = f2bf(fmaxf(a + 0.1f * acc[m][n][j] - 0.1f * (a - tp), 0.f));
        }
  } else if (d.mode == M_PRED) {
#pragma unroll
    for (int m = 0; m < 4; ++m)
#pragma unroll
      for (int n = 0; n < 4; ++n)
#pragma unroll
        for (int j = 0; j < 4; ++j) {
          const size_t idx = IDX;
          float t = fast_tanh(acc[m][n][j]);
          d.o0[idx] = f2bf(t);
          float an = bf2f(d.i0[idx]);
          d.o1[idx] = f2bf((an - t) * (1.f - t * t));
        }
  } else {  // M_PART
    float* po = d.fout + (size_t)sk * 2048 * N;
#pragma unroll
    for (int m = 0; m < 4; ++m)
#pragma unroll
      for (int n = 0; n < 4; ++n)
#pragma unroll
        for (int j = 0; j < 4; ++j) {
          const size_t idx = IDX;
          po[idx] = acc[m][n][j];
        }
  }
#undef IDX
}

// ---------------- split-K combine: sum partials -> sigmoid -> d3, out ----------
__global__ void k_comb(const float* __restrict__ psum, const float* __restrict__ targ,
                       unsigned short* __restrict__ d3, float* __restrict__ out,
                       int n4, int ks) {
  const size_t plane4 = (size_t)2048 * 1024 / 4;
  int i = blockIdx.x * blockDim.x + threadIdx.x, st = gridDim.x * blockDim.x;
  for (; i < n4; i += st) {
    float4 s0 = ((const float4*)psum)[i];
    for (int s = 1; s < ks; ++s) {
      float4 sv = ((const float4*)psum)[i + s * plane4];
      s0.x += sv.x; s0.y += sv.y; s0.z += sv.z; s0.w += sv.w;
    }
    float4 tv = ((const float4*)targ)[i];
    float4 o; ushort4 dv; float sg;
    sg = fast_sig(s0.x); o.x = sg; dv.x = f2bf((tv.x - sg) * sg * (1.f - sg));
    sg = fast_sig(s0.y); o.y = sg; dv.y = f2bf((tv.y - sg) * sg * (1.f - sg));
    sg = fast_sig(s0.z); o.z = sg; dv.z = f2bf((tv.z - sg) * sg * (1.f - sg));
    sg = fast_sig(s0.w); o.w = sg; dv.w = f2bf((tv.w - sg) * sg * (1.f - sg));
    ((float4*)out)[i] = o;
    ((ushort4*)d3)[i] = dv;
  }
}

// ---------------- batched f32 -> bf16 conversion (8 jobs, one launch) ----------
struct CvtJobs {
  const float* src[8];
  unsigned short* dst[8];
  int n4[8];
};
__global__ void k_cvt8(CvtJobs J) {
  const int jb = blockIdx.y;
  const float* s = J.src[jb];
  unsigned short* dd = J.dst[jb];
  const int n4 = J.n4[jb];
  int i = blockIdx.x * blockDim.x + threadIdx.x, st = gridDim.x * blockDim.x;
  for (; i < n4; i += st) {
    float4 v = ((const float4*)s)[i];
    ushort4 o; o.x = f2bf(v.x); o.y = f2bf(v.y); o.z = f2bf(v.z); o.w = f2bf(v.w);
    ((ushort4*)dd)[i] = o;
  }
}

// ------------------------------------------------------------------------------------
extern "C" void kernel_launch(void* const* d_in, const int* in_sizes, int n_in,
                              void* d_out, int out_size, void* d_ws, size_t ws_size,
                              hipStream_t stream) {
  (void)in_sizes; (void)n_in; (void)out_size;
  const float* x      = (const float*)d_in[0];
  const float* target = (const float*)d_in[1];
  const float* wSrc[7] = {(const float*)d_in[2], (const float*)d_in[3],
                          (const float*)d_in[4], (const float*)d_in[5],
                          (const float*)d_in[6], (const float*)d_in[7],
                          (const float*)d_in[8]};
  const size_t wN[7] = {(size_t)4096 * 1024, (size_t)4096 * 4096, (size_t)4096 * 4096,
                        (size_t)1024 * 4096, (size_t)4096 * 4096, (size_t)4096 * 4096,
                        (size_t)4096 * 1024};

  char* w = (char*)d_ws;
  size_t off = 0;
  auto alloc = [&](size_t bytes) { void* p = w + off; off += bytes; return p; };

  const size_t BIG = (size_t)B_ * 4096;
  const size_t SML = (size_t)B_ * 1024;
  unsigned short* xb  = (unsigned short*)alloc(SML * 2);
  unsigned short* a1b = (unsigned short*)alloc(BIG * 2);
  unsigned short* a2b = (unsigned short*)alloc(BIG * 2);
  unsigned short* a3b = (unsigned short*)alloc(BIG * 2);
  unsigned short* t0b = (unsigned short*)alloc(BIG * 2);
  unsigned short* t1b = (unsigned short*)alloc(BIG * 2);
  unsigned short* t2b = (unsigned short*)alloc(BIG * 2);
  unsigned short* d1b = (unsigned short*)alloc(BIG * 2);
  unsigned short* d2b = (unsigned short*)alloc(BIG * 2);
  unsigned short* d3b = (unsigned short*)alloc(SML * 2);
  unsigned short* Wb[7];
  for (int i = 0; i < 7; ++i) Wb[i] = (unsigned short*)alloc(wN[i] * 2);

  // split-K partials for the N=1024 legs (p2/g3)
  const size_t PS = SML * 4;  // 8 MB per split plane
  int KS = 1;
  if (ws_size >= off + 4 * PS) KS = 4;
  else if (ws_size >= off + 2 * PS) KS = 2;
  float* psum = (KS > 1) ? (float*)alloc((size_t)KS * PS) : nullptr;

  // ---- conversions: one batched launch ----
  CvtJobs J;
  for (int i = 0; i < 7; ++i) { J.src[i] = wSrc[i]; J.dst[i] = Wb[i]; J.n4[i] = (int)(wN[i] >> 2); }
  J.src[7] = x; J.dst[7] = xb; J.n4[7] = (int)(SML >> 2);
  k_cvt8<<<dim3(2048, 8), 256, 0, stream>>>(J);

  float* out = (float*)d_out;
  const int n4_sml = (int)(SML >> 2);
  auto desc = [&](const unsigned short* A, const unsigned short* W_, int K, int knt,
                  int N, int mode, unsigned short* o0, unsigned short* o1,
                  unsigned short* o2, const unsigned short* i0, const float* targ,
                  float* fout) {
    GDesc g; g.A = A; g.W = W_; g.o0 = o0; g.o1 = o1; g.o2 = o2; g.i0 = i0;
    g.targ = targ; g.fout = fout; g.K = K; g.knt = knt; g.N = N; g.mode = mode;
    return g;
  };
  auto launch_sig_leg = [&](const unsigned short* A) {
    if (KS > 1) {
      GDesc g = desc(A, Wb[3], 4096, 64 / KS, 1024, M_PART,
                     nullptr, nullptr, nullptr, nullptr, nullptr, psum);
      gemm128<<<dim3(8, 16 * KS, 1), 256, 0, stream>>>(g, g, g);
      k_comb<<<2048, 256, 0, stream>>>(psum, target, d3b, out, n4_sml, KS);
    } else {
      GDesc g = desc(A, Wb[3], 4096, 64, 1024, M_SIG,
                     d3b, nullptr, nullptr, nullptr, target, out);
      gemm128<<<dim3(8, 16, 1), 256, 0, stream>>>(g, g, g);
    }
  };

  // ---- initial feedforward (gemm128: balanced 512-block grids) ----
  {
    GDesc g0 = desc(xb,  Wb[0], 1024, 16, 4096, M_ACT,  t0b, a1b, nullptr, nullptr, nullptr, nullptr);
    gemm128<<<dim3(32, 16, 1), 256, 0, stream>>>(g0, g0, g0);
    GDesc g1 = desc(a1b, Wb[1], 4096, 64, 4096, M_ACTD, t1b, a2b, d1b, nullptr, nullptr, nullptr);
    gemm128<<<dim3(32, 16, 1), 256, 0, stream>>>(g1, g1, g1);
    GDesc g2 = desc(a2b, Wb[2], 4096, 64, 4096, M_ACTD, t2b, a3b, d2b, nullptr, nullptr, nullptr);
    gemm128<<<dim3(32, 16, 1), 256, 0, stream>>>(g2, g2, g2);
    launch_sig_leg(a3b);
  }

  // ---- 5 inference iterations ----
  for (int it = 0; it < 5; ++it) {
    // L1: balanced 8-phase pair {e0,e1} -- exactly 256 blocks, 1/CU
    GDesc e0 = desc(d1b, Wb[4], 4096, 64, 4096, M_ERR, a1b, nullptr, nullptr, t0b, nullptr, nullptr);
    GDesc e1 = desc(d2b, Wb[5], 4096, 64, 4096, M_ERR, a2b, nullptr, nullptr, t1b, nullptr, nullptr);
    gemm8p<<<dim3(16, 8, 2), 512, LDS_BYTES, stream>>>(e0, e1, e1);
    // L2: e2 (K=1024) on gemm128 -- 512 blocks, 2/CU, full width
    GDesc e2 = desc(d3b, Wb[6], 1024, 16, 4096, M_ERR, a3b, nullptr, nullptr, t2b, nullptr, nullptr);
    gemm128<<<dim3(32, 16, 1), 256, 0, stream>>>(e2, e2, e2);
    // L3: balanced 8-phase pair {p0,p1} -- exactly 256 blocks
    GDesc p0 = desc(a1b, Wb[1], 4096, 64, 4096, M_PRED, t1b, d1b, nullptr, a2b, nullptr, nullptr);
    GDesc p1 = desc(a2b, Wb[2], 4096, 64, 4096, M_PRED, t2b, d2b, nullptr, a3b, nullptr, nullptr);
    gemm8p<<<dim3(16, 8, 2), 512, LDS_BYTES, stream>>>(p0, p1, p1);
    // L4/L5: p2 split-K + combine
    launch_sig_leg(a3b);
  }
}

// Round 11
// 1792.349 us; speedup vs baseline: 1.4941x; 1.2529x over previous
//
#include <hip/hip_runtime.h>
#include <stdint.h>

// Predictive-coding inference: LAYER_SZS=[1024,4096,4096,4096,1024], B=2048, 5 iters.
// GEMM: C[M,N] = A[M,K](bf16) @ W[N,K](bf16)^T, f32 accum, fused epilogues.
// gemm128 (m97-structure, 797 TF measured batched): 128x128 tile, BK=64, 4 waves,
// single-buffered 32KB LDS, XOR bank-swizzle (0 conflicts). Overlap via 2-6
// independent blocks/CU.
// KEY CHANGE (R11): dead-code elimination across iterations. Backward slice from
// out = sigmoid(a3_5 @ Wf3):
//   iter 5: only e2-leg + sig-leg live (a1/a2 updates, p1/p2 recomputes dead)
//   iter 4: e0-leg dead (a1_4 only feeds dead p0_4); p0-leg dead (t1_4/d1_4 feed
//           only dead iter-5 legs)
//   iters 1-3: fully live.
// Removes ~500us of measured GEMM time with zero numerics/schedule risk.

typedef __attribute__((ext_vector_type(8))) __bf16 bf16x8;
typedef __attribute__((ext_vector_type(4))) float f32x4;

#define B_ 2048

__device__ __forceinline__ unsigned short f2bf(float f) {
  union { float f; unsigned u; } v; v.f = f;
  unsigned u = v.u;
  u += 0x7FFFu + ((u >> 16) & 1u);
  return (unsigned short)(u >> 16);
}
__device__ __forceinline__ float bf2f(unsigned short s) {
  union { unsigned u; float f; } v; v.u = ((unsigned)s) << 16;
  return v.f;
}
__device__ __forceinline__ float fast_sig(float x) { return 1.0f / (1.0f + __expf(-x)); }
__device__ __forceinline__ float fast_tanh(float x) {
  return 1.0f - 2.0f / (__expf(2.0f * x) + 1.0f);
}
__device__ __forceinline__ void gload_lds16(const void* g, void* l) {
  __builtin_amdgcn_global_load_lds((const __attribute__((address_space(1))) void*)g,
                                   (__attribute__((address_space(3))) void*)l, 16, 0, 0);
}

// epilogue modes
#define M_ACT  0   // o0=t=tanh(acc); o1=relu(t)
#define M_ACTD 1   // + o2 = d = (relu(t)-t)(1-t^2)
#define M_SIG  2   // s=sig(acc); o0=(targ-s)s(1-s); fout=s
#define M_ERR  3   // o0(a) = relu(a + 0.1*acc - 0.1*(a - i0))
#define M_PRED 4   // t=tanh(acc); o0=t; o1=(i0 - t)(1-t^2)
#define M_PART 5   // fout[sk-plane] = acc (f32 partial sums, split-K)

struct GDesc {
  const unsigned short* A;   // [M,K]
  const unsigned short* W;   // [N,K]
  unsigned short* o0;
  unsigned short* o1;
  unsigned short* o2;
  const unsigned short* i0;
  const float* targ;
  float* fout;
  int K;     // row stride (elements)
  int knt;   // K-tiles (BK=64) per block
  int N, mode;
};

__global__ __launch_bounds__(256, 4) void gemm128(GDesc d0, GDesc d1, GDesc d2) {
  const GDesc d = (blockIdx.z == 0) ? d0 : (blockIdx.z == 1 ? d1 : d2);

  __shared__ alignas(16) unsigned short As[128 * 64];
  __shared__ alignas(16) unsigned short Bs[128 * 64];

  const int tid = threadIdx.x;
  const int wid = tid >> 6, lane = tid & 63;
  const int wr = wid >> 1, wc = wid & 1;      // 2 x 2 waves
  const int q = lane >> 4, j16 = lane & 15, r3 = j16 & 7;
  const int K = d.K, N = d.N, nt = d.knt;

  const int sk  = blockIdx.y >> 4;            // split-K plane (0 unless split leg)
  const int row0 = (blockIdx.y & 15) << 7;    // BM = 128
  const int col0 = blockIdx.x << 7;           // BN = 128
  const int kbeg = (sk * nt) << 6;

  // staging: thread covers rows rbase+32*i, 16B chunk (tid&7); global source
  // chunk XOR-swizzled by row&7; LDS dest linear (HW adds lane*16B)
  const int rbase = (wid << 3) + (lane >> 3);                 // 0..31
  const int csw   = ((lane & 7) ^ ((lane >> 3) & 7)) << 3;    // swizzled chunk
  const unsigned short* Ag = d.A + (size_t)row0 * K;
  const unsigned short* Bg = d.W + (size_t)col0 * K;
  const int ldst = wid << 9;

  // LDS read offsets (shorts), loop-invariant; swizzle matches staging
  int aoff[4][2], boff[4][2];
#pragma unroll
  for (int m = 0; m < 4; ++m)
#pragma unroll
    for (int ks = 0; ks < 2; ++ks) {
      aoff[m][ks] = (wr * 64 + m * 16 + j16) * 64 + (((ks * 4 + q) ^ r3) << 3);
      boff[m][ks] = (wc * 64 + m * 16 + j16) * 64 + (((ks * 4 + q) ^ r3) << 3);
    }

  f32x4 acc[4][4];
#pragma unroll
  for (int m = 0; m < 4; ++m)
#pragma unroll
    for (int n = 0; n < 4; ++n) acc[m][n] = (f32x4){0.f, 0.f, 0.f, 0.f};

  for (int t = 0; t < nt; ++t) {
    const int k0 = kbeg + (t << 6);
#pragma unroll
    for (int i = 0; i < 4; ++i)
      gload_lds16(Ag + (size_t)((i << 5) + rbase) * K + k0 + csw,
                  As + (i << 11) + ldst);
#pragma unroll
    for (int i = 0; i < 4; ++i)
      gload_lds16(Bg + (size_t)((i << 5) + rbase) * K + k0 + csw,
                  Bs + (i << 11) + ldst);
    asm volatile("s_waitcnt vmcnt(0)" ::: "memory");
    __builtin_amdgcn_s_barrier();

#pragma unroll
    for (int ks = 0; ks < 2; ++ks) {
      bf16x8 av[4], bv[4];
#pragma unroll
      for (int m = 0; m < 4; ++m) av[m] = *(const bf16x8*)(As + aoff[m][ks]);
#pragma unroll
      for (int n = 0; n < 4; ++n) bv[n] = *(const bf16x8*)(Bs + boff[n][ks]);
#pragma unroll
      for (int m = 0; m < 4; ++m)
#pragma unroll
        for (int n = 0; n < 4; ++n)
          acc[m][n] = __builtin_amdgcn_mfma_f32_16x16x32_bf16(av[m], bv[n], acc[m][n], 0, 0, 0);
    }
    __builtin_amdgcn_s_barrier();
  }

  // epilogue: D row=(lane>>4)*4+j, col=lane&15 (m89-verified layout)
#define IDX (size_t)(row0 + wr * 64 + m * 16 + (q << 2) + j) * N \
          + (col0 + wc * 64 + n * 16 + j16)
  if (d.mode == M_ACT) {
#pragma unroll
    for (int m = 0; m < 4; ++m)
#pragma unroll
      for (int n = 0; n < 4; ++n)
#pragma unroll
        for (int j = 0; j < 4; ++j) {
          const size_t idx = IDX;
          float t = fast_tanh(acc[m][n][j]);
          d.o0[idx] = f2bf(t);
          d.o1[idx] = f2bf(fmaxf(t, 0.f));
        }
  } else if (d.mode == M_ACTD) {
#pragma unroll
    for (int m = 0; m < 4; ++m)
#pragma unroll
      for (int n = 0; n < 4; ++n)
#pragma unroll
        for (int j = 0; j < 4; ++j) {
          const size_t idx = IDX;
          float t = fast_tanh(acc[m][n][j]);
          d.o0[idx] = f2bf(t);
          d.o1[idx] = f2bf(fmaxf(t, 0.f));
          d.o2[idx] = f2bf(t >= 0.f ? 0.f : (-t) * (1.f - t * t));
        }
  } else if (d.mode == M_SIG) {
#pragma unroll
    for (int m = 0; m < 4; ++m)
#pragma unroll
      for (int n = 0; n < 4; ++n)
#pragma unroll
        for (int j = 0; j < 4; ++j) {
          const size_t idx = IDX;
          float s = fast_sig(acc[m][n][j]);
          d.fout[idx] = s;
          d.o0[idx] = f2bf((d.targ[idx] - s) * s * (1.f - s));
        }
  } else if (d.mode == M_ERR) {
#pragma unroll
    for (int m = 0; m < 4; ++m)
#pragma unroll
      for (int n = 0; n < 4; ++n)
#pragma unroll
        for (int j = 0; j < 4; ++j) {
          const size_t idx = IDX;
          float a = bf2f(d.o0[idx]);
          float tp = bf2f(d.i0[idx]);
          d.o0[idx] = f2bf(fmaxf(a + 0.1f * acc[m][n][j] - 0.1f * (a - tp), 0.f));
        }
  } else if (d.mode == M_PRED) {
#pragma unroll
    for (int m = 0; m < 4; ++m)
#pragma unroll
      for (int n = 0; n < 4; ++n)
#pragma unroll
        for (int j = 0; j < 4; ++j) {
          const size_t idx = IDX;
          float t = fast_tanh(acc[m][n][j]);
          d.o0[idx] = f2bf(t);
          float an = bf2f(d.i0[idx]);
          d.o1[idx] = f2bf((an - t) * (1.f - t * t));
        }
  } else {  // M_PART
    float* po = d.fout + (size_t)sk * 2048 * N;
#pragma unroll
    for (int m = 0; m < 4; ++m)
#pragma unroll
      for (int n = 0; n < 4; ++n)
#pragma unroll
        for (int j = 0; j < 4; ++j) {
          const size_t idx = IDX;
          po[idx] = acc[m][n][j];
        }
  }
#undef IDX
}

// ---------------- split-K combine: sum partials -> sigmoid -> d3, out ----------
__global__ void k_comb(const float* __restrict__ psum, const float* __restrict__ targ,
                       unsigned short* __restrict__ d3, float* __restrict__ out,
                       int n4, int ks) {
  const size_t plane4 = (size_t)2048 * 1024 / 4;
  int i = blockIdx.x * blockDim.x + threadIdx.x, st = gridDim.x * blockDim.x;
  for (; i < n4; i += st) {
    float4 s0 = ((const float4*)psum)[i];
    for (int s = 1; s < ks; ++s) {
      float4 sv = ((const float4*)psum)[i + s * plane4];
      s0.x += sv.x; s0.y += sv.y; s0.z += sv.z; s0.w += sv.w;
    }
    float4 tv = ((const float4*)targ)[i];
    float4 o; ushort4 dv; float sg;
    sg = fast_sig(s0.x); o.x = sg; dv.x = f2bf((tv.x - sg) * sg * (1.f - sg));
    sg = fast_sig(s0.y); o.y = sg; dv.y = f2bf((tv.y - sg) * sg * (1.f - sg));
    sg = fast_sig(s0.z); o.z = sg; dv.z = f2bf((tv.z - sg) * sg * (1.f - sg));
    sg = fast_sig(s0.w); o.w = sg; dv.w = f2bf((tv.w - sg) * sg * (1.f - sg));
    ((float4*)out)[i] = o;
    ((ushort4*)d3)[i] = dv;
  }
}

// ---------------- batched f32 -> bf16 conversion (8 jobs, one launch) ----------
struct CvtJobs {
  const float* src[8];
  unsigned short* dst[8];
  int n4[8];
};
__global__ void k_cvt8(CvtJobs J) {
  const int jb = blockIdx.y;
  const float* s = J.src[jb];
  unsigned short* dd = J.dst[jb];
  const int n4 = J.n4[jb];
  int i = blockIdx.x * blockDim.x + threadIdx.x, st = gridDim.x * blockDim.x;
  for (; i < n4; i += st) {
    float4 v = ((const float4*)s)[i];
    ushort4 o; o.x = f2bf(v.x); o.y = f2bf(v.y); o.z = f2bf(v.z); o.w = f2bf(v.w);
    ((ushort4*)dd)[i] = o;
  }
}

// ------------------------------------------------------------------------------------
extern "C" void kernel_launch(void* const* d_in, const int* in_sizes, int n_in,
                              void* d_out, int out_size, void* d_ws, size_t ws_size,
                              hipStream_t stream) {
  (void)in_sizes; (void)n_in; (void)out_size;
  const float* x      = (const float*)d_in[0];
  const float* target = (const float*)d_in[1];
  const float* wSrc[7] = {(const float*)d_in[2], (const float*)d_in[3],
                          (const float*)d_in[4], (const float*)d_in[5],
                          (const float*)d_in[6], (const float*)d_in[7],
                          (const float*)d_in[8]};
  const size_t wN[7] = {(size_t)4096 * 1024, (size_t)4096 * 4096, (size_t)4096 * 4096,
                        (size_t)1024 * 4096, (size_t)4096 * 4096, (size_t)4096 * 4096,
                        (size_t)4096 * 1024};

  char* w = (char*)d_ws;
  size_t off = 0;
  auto alloc = [&](size_t bytes) { void* p = w + off; off += bytes; return p; };

  const size_t BIG = (size_t)B_ * 4096;
  const size_t SML = (size_t)B_ * 1024;
  unsigned short* xb  = (unsigned short*)alloc(SML * 2);
  unsigned short* a1b = (unsigned short*)alloc(BIG * 2);
  unsigned short* a2b = (unsigned short*)alloc(BIG * 2);
  unsigned short* a3b = (unsigned short*)alloc(BIG * 2);
  unsigned short* t0b = (unsigned short*)alloc(BIG * 2);
  unsigned short* t1b = (unsigned short*)alloc(BIG * 2);
  unsigned short* t2b = (unsigned short*)alloc(BIG * 2);
  unsigned short* d1b = (unsigned short*)alloc(BIG * 2);
  unsigned short* d2b = (unsigned short*)alloc(BIG * 2);
  unsigned short* d3b = (unsigned short*)alloc(SML * 2);
  unsigned short* Wb[7];
  for (int i = 0; i < 7; ++i) Wb[i] = (unsigned short*)alloc(wN[i] * 2);

  // split-K partials for the N=1024 legs (p2/g3)
  const size_t PS = SML * 4;  // 8 MB per split plane
  int KS = 1;
  if (ws_size >= off + 4 * PS) KS = 4;
  else if (ws_size >= off + 2 * PS) KS = 2;
  float* psum = (KS > 1) ? (float*)alloc((size_t)KS * PS) : nullptr;

  // ---- conversions: one batched launch ----
  CvtJobs J;
  for (int i = 0; i < 7; ++i) { J.src[i] = wSrc[i]; J.dst[i] = Wb[i]; J.n4[i] = (int)(wN[i] >> 2); }
  J.src[7] = x; J.dst[7] = xb; J.n4[7] = (int)(SML >> 2);
  k_cvt8<<<dim3(2048, 8), 256, 0, stream>>>(J);

  float* out = (float*)d_out;
  const int n4_sml = (int)(SML >> 2);
  auto desc = [&](const unsigned short* A, const unsigned short* W_, int K, int knt,
                  int N, int mode, unsigned short* o0, unsigned short* o1,
                  unsigned short* o2, const unsigned short* i0, const float* targ,
                  float* fout) {
    GDesc g; g.A = A; g.W = W_; g.o0 = o0; g.o1 = o1; g.o2 = o2; g.i0 = i0;
    g.targ = targ; g.fout = fout; g.K = K; g.knt = knt; g.N = N; g.mode = mode;
    return g;
  };
  auto launch_sig_leg = [&](const unsigned short* A) {
    if (KS > 1) {
      GDesc g = desc(A, Wb[3], 4096, 64 / KS, 1024, M_PART,
                     nullptr, nullptr, nullptr, nullptr, nullptr, psum);
      gemm128<<<dim3(8, 16 * KS, 1), 256, 0, stream>>>(g, g, g);
      k_comb<<<2048, 256, 0, stream>>>(psum, target, d3b, out, n4_sml, KS);
    } else {
      GDesc g = desc(A, Wb[3], 4096, 64, 1024, M_SIG,
                     d3b, nullptr, nullptr, nullptr, target, out);
      gemm128<<<dim3(8, 16, 1), 256, 0, stream>>>(g, g, g);
    }
  };

  // ---- initial feedforward ----
  {
    GDesc g0 = desc(xb,  Wb[0], 1024, 16, 4096, M_ACT,  t0b, a1b, nullptr, nullptr, nullptr, nullptr);
    gemm128<<<dim3(32, 16, 1), 256, 0, stream>>>(g0, g0, g0);
    GDesc g1 = desc(a1b, Wb[1], 4096, 64, 4096, M_ACTD, t1b, a2b, d1b, nullptr, nullptr, nullptr);
    gemm128<<<dim3(32, 16, 1), 256, 0, stream>>>(g1, g1, g1);
    GDesc g2 = desc(a2b, Wb[2], 4096, 64, 4096, M_ACTD, t2b, a3b, d2b, nullptr, nullptr, nullptr);
    gemm128<<<dim3(32, 16, 1), 256, 0, stream>>>(g2, g2, g2);
    launch_sig_leg(a3b);
  }

  // ---- 5 inference iterations with dead-leg pruning ----
  // leg descriptors (identical每iteration; rebuilt for clarity)
  for (int it = 1; it <= 5; ++it) {
    GDesc e0 = desc(d1b, Wb[4], 4096, 64, 4096, M_ERR, a1b, nullptr, nullptr, t0b, nullptr, nullptr);
    GDesc e1 = desc(d2b, Wb[5], 4096, 64, 4096, M_ERR, a2b, nullptr, nullptr, t1b, nullptr, nullptr);
    GDesc e2 = desc(d3b, Wb[6], 1024, 16, 4096, M_ERR, a3b, nullptr, nullptr, t2b, nullptr, nullptr);
    GDesc p0 = desc(a1b, Wb[1], 4096, 64, 4096, M_PRED, t1b, d1b, nullptr, a2b, nullptr, nullptr);
    GDesc p1 = desc(a2b, Wb[2], 4096, 64, 4096, M_PRED, t2b, d2b, nullptr, a3b, nullptr, nullptr);
    if (it <= 3) {
      // full iteration: E {e0,e1,e2} batched (1536 blk), P {p0,p1} (1024 blk)
      gemm128<<<dim3(32, 16, 3), 256, 0, stream>>>(e0, e1, e2);
      gemm128<<<dim3(32, 16, 2), 256, 0, stream>>>(p0, p1, p1);
      launch_sig_leg(a3b);
    } else if (it == 4) {
      // e0 dead (a1_4 only feeds dead p0_4); p0 dead (t1_4/d1_4 feed dead iter-5 legs)
      gemm128<<<dim3(32, 16, 2), 256, 0, stream>>>(e1, e2, e2);
      gemm128<<<dim3(32, 16, 1), 256, 0, stream>>>(p1, p1, p1);
      launch_sig_leg(a3b);
    } else {
      // iter 5: only a3 update + final output leg live
      gemm128<<<dim3(32, 16, 1), 256, 0, stream>>>(e2, e2, e2);
      launch_sig_leg(a3b);
    }
  }
}